// Round 11
// baseline (312.630 us; speedup 1.0000x reference)
//
#include <hip/hip_runtime.h>
#include <hip/hip_bf16.h>
#include <math.h>

typedef __bf16 bf16_t;
typedef __bf16 bf16x2 __attribute__((ext_vector_type(2)));
typedef __bf16 bf16x4 __attribute__((ext_vector_type(4)));
typedef __bf16 bf16x8 __attribute__((ext_vector_type(8)));
typedef float f32x4 __attribute__((ext_vector_type(4)));

#define SEQ 2048
#define MLA_SCALE 0.07216878364870322f
#define LN_EPS 1e-5f

__device__ __forceinline__ void gload_lds16(const bf16_t* g, bf16_t* l) {
    __builtin_amdgcn_global_load_lds(
        (const __attribute__((address_space(1))) uint32_t*)(const void*)g,
        (__attribute__((address_space(3))) uint32_t*)(void*)l, 16, 0, 0);
}

// bijective XCD-aware block swizzle
__device__ __forceinline__ void xcd_map(int bid, int total, int nbn,
                                        int& bm, int& bn) {
    int per = total >> 3;
    int cbm = per / nbn;
    int xcd = bid & 7, s = bid >> 3;
    int q = s / nbn;
    bm = xcd * cbm + q;
    bn = s - q * nbn;
}

// ---------------------------------------------------------------------------
// fused fp32 -> bf16 convert of all 5 buffers (one launch)
// ---------------------------------------------------------------------------
#define CVT_N0 2097152   // x      (float4 units)
#define CVT_N1 1572864   // wq
#define CVT_N2 294912    // wkv_a
#define CVT_N3 524288    // wkv_b
#define CVT_N4 1048576   // wo
#define CVT_TOT (CVT_N0 + CVT_N1 + CVT_N2 + CVT_N3 + CVT_N4)

__global__ __launch_bounds__(256)
void cvt_all(const float* __restrict__ x, const float* __restrict__ wq,
             const float* __restrict__ wa, const float* __restrict__ wb,
             const float* __restrict__ wo, bf16_t* __restrict__ xb,
             bf16_t* __restrict__ wqb, bf16_t* __restrict__ wab,
             bf16_t* __restrict__ wbb, bf16_t* __restrict__ wob) {
    for (int i = blockIdx.x * 256 + threadIdx.x; i < CVT_TOT; i += gridDim.x * 256) {
        const float* src; bf16_t* dst; int off = i;
        if (i < CVT_N0) { src = x; dst = xb; }
        else if (i < CVT_N0 + CVT_N1) { src = wq; dst = wqb; off = i - CVT_N0; }
        else if (i < CVT_N0 + CVT_N1 + CVT_N2) { src = wa; dst = wab; off = i - CVT_N0 - CVT_N1; }
        else if (i < CVT_N0 + CVT_N1 + CVT_N2 + CVT_N3) { src = wb; dst = wbb; off = i - CVT_N0 - CVT_N1 - CVT_N2; }
        else { src = wo; dst = wob; off = i - CVT_N0 - CVT_N1 - CVT_N2 - CVT_N3; }
        float4 v = ((const float4*)src)[off];
        bf16x4 p = { (bf16_t)v.x, (bf16_t)v.y, (bf16_t)v.z, (bf16_t)v.w };
        ((bf16x4*)dst)[off] = p;
    }
}

// ===========================================================================
// 256x256 8-phase GEMM. C[M,N] = A[M,K] * B[N,K]^T, bf16 in, fp32 acc.
// MODE 0: fp32 C.  MODE 1: kvb pack (K_pack + Vt).  MODE 2: q bf16 head-major.
// ===========================================================================
#define G256_PHASE(TAU, KS, MH, HTO, MAT, WAITV)                               \
{                                                                              \
    const int slot_ = (2 * (TAU) + (KS)) & 3;                                  \
    bf16x8 af_[4];                                                             \
    {                                                                          \
        const bf16_t* ab_ = As + slot_ * 8192 +                                \
                            (wm2 * 128 + (MH) * 64 + lr) * 32 + rdcol;         \
        _Pragma("unroll")                                                      \
        for (int f = 0; f < 4; ++f) af_[f] = *(const bf16x8*)(ab_ + f * 512);  \
    }                                                                          \
    if ((MH) == 0) {                                                           \
        const bf16_t* bb_ = Bs + slot_ * 8192 + (wn2 * 64 + lr) * 32 + rdcol;  \
        _Pragma("unroll")                                                      \
        for (int f = 0; f < 4; ++f) bq[f] = *(const bf16x8*)(bb_ + f * 512);   \
    }                                                                          \
    if ((MAT) == 0) stageA(2 * T + 3 + (HTO)); else stageB(2 * T + 3 + (HTO)); \
    __builtin_amdgcn_s_barrier();                                              \
    asm volatile("" ::: "memory");                                             \
    __builtin_amdgcn_s_setprio(1);                                             \
    _Pragma("unroll")                                                          \
    for (int f = 0; f < 4; ++f)                                                \
        _Pragma("unroll")                                                      \
        for (int n = 0; n < 4; ++n)                                            \
            acc[(MH) * 4 + f][n] = __builtin_amdgcn_mfma_f32_16x16x32_bf16(    \
                af_[f], bq[n], acc[(MH) * 4 + f][n], 0, 0, 0);                 \
    __builtin_amdgcn_s_setprio(0);                                             \
    asm volatile("" ::: "memory");                                             \
    if (WAITV) asm volatile("s_waitcnt vmcnt(8)" ::: "memory");                \
    __builtin_amdgcn_s_barrier();                                              \
}

template<int MODE>
__global__ __launch_bounds__(512, 2)
void gemm256(const bf16_t* __restrict__ A, const bf16_t* __restrict__ B,
             float* __restrict__ C, bf16_t* __restrict__ out0,
             bf16_t* __restrict__ out1, int N, int K, int total, int nbn) {
    __shared__ __attribute__((aligned(16))) bf16_t As[32768];
    __shared__ __attribute__((aligned(16))) bf16_t Bs[32768];
    __shared__ __attribute__((aligned(16))) bf16_t Ds[8192];

    const int tid = threadIdx.x;
    const int lane = tid & 63, w = tid >> 6;
    const int lr = lane & 15, kh = lane >> 4;
    const int wm2 = w >> 2, wn2 = w & 3;
    int bm, bn;
    xcd_map(blockIdx.x, total, nbn, bm, bn);
    const int NT = K >> 6;

    const int rdcol = 8 * (kh ^ ((lr >> 1) & 3));
    const int strow = (w << 5) + (lane >> 2);
    const int scol = 8 * ((lane & 3) ^ ((lane >> 3) & 3));

    f32x4 acc[8][4];
    #pragma unroll
    for (int i = 0; i < 8; ++i)
        #pragma unroll
        for (int j = 0; j < 4; ++j) acc[i][j] = 0.0f;

    auto stageA = [&](int ht) {
        int hs = (ht < 2 * NT) ? ht : (2 * NT - 1);
        int tau = hs >> 1, kap = hs & 1;
        const bf16_t* g = A + (size_t)(bm * 256 + strow) * K + tau * 64 + kap * 32 + scol;
        bf16_t* l = (ht < 2 * NT) ? (As + (ht & 3) * 8192 + w * 1024) : (Ds + w * 1024);
        gload_lds16(g, l);
        gload_lds16(g + (size_t)16 * K, l + 512);
    };
    auto stageB = [&](int ht) {
        int hs = (ht < 2 * NT) ? ht : (2 * NT - 1);
        int tau = hs >> 1, kap = hs & 1;
        const bf16_t* g = B + (size_t)(bn * 256 + strow) * K + tau * 64 + kap * 32 + scol;
        bf16_t* l = (ht < 2 * NT) ? (Bs + (ht & 3) * 8192 + w * 1024) : (Ds + w * 1024);
        gload_lds16(g, l);
        gload_lds16(g + (size_t)16 * K, l + 512);
    };

    stageA(0); stageB(0); stageA(1); stageB(1); stageA(2); stageB(2);
    asm volatile("s_waitcnt vmcnt(8)" ::: "memory");
    __builtin_amdgcn_s_barrier();

    for (int it = 0; it < (NT >> 1); ++it) {
        const int T = 2 * it;
        bf16x8 bq[4];
        G256_PHASE(T,     0, 0, 0, 0, 0)
        G256_PHASE(T,     0, 1, 0, 1, 1)
        G256_PHASE(T,     1, 0, 1, 0, 0)
        G256_PHASE(T,     1, 1, 1, 1, 1)
        G256_PHASE(T + 1, 0, 0, 2, 0, 0)
        G256_PHASE(T + 1, 0, 1, 2, 1, 1)
        G256_PHASE(T + 1, 1, 0, 3, 0, 0)
        G256_PHASE(T + 1, 1, 1, 3, 1, 1)
    }

    const int rg = kh * 4;
    if (MODE == 0) {
        #pragma unroll
        for (int mf = 0; mf < 8; ++mf)
            #pragma unroll
            for (int nf = 0; nf < 4; ++nf) {
                size_t row0 = (size_t)(bm * 256 + wm2 * 128 + mf * 16 + rg);
                int col = bn * 256 + wn2 * 64 + nf * 16 + lr;
                #pragma unroll
                for (int rr = 0; rr < 4; ++rr)
                    C[(row0 + rr) * N + col] = acc[mf][nf][rr];
            }
    } else if (MODE == 1) {
        const int h = bn;
        #pragma unroll
        for (int mf = 0; mf < 8; ++mf)
            #pragma unroll
            for (int nf = 0; nf < 4; ++nf) {
                int d = wn2 * 64 + nf * 16 + lr;
                int trow = bm * 256 + wm2 * 128 + mf * 16 + rg;
                int b = trow >> 11, t = trow & 2047;
                if (d < 128) {
                    bf16_t* p = out0 + ((size_t)(b * 16 + h) * SEQ + t) * 192 + d;
                    #pragma unroll
                    for (int rr = 0; rr < 4; ++rr)
                        p[rr * 192] = (bf16_t)acc[mf][nf][rr];
                } else {
                    bf16x4 pv = { (bf16_t)acc[mf][nf][0], (bf16_t)acc[mf][nf][1],
                                  (bf16_t)acc[mf][nf][2], (bf16_t)acc[mf][nf][3] };
                    *(bf16x4*)(out1 + ((size_t)(b * 16 + h) * 128 + (d - 128)) * SEQ + t) = pv;
                }
            }
    } else {
        #pragma unroll
        for (int mf = 0; mf < 8; ++mf)
            #pragma unroll
            for (int nf = 0; nf < 4; ++nf) {
                int n = bn * 256 + wn2 * 64 + nf * 16 + lr;
                int h = n / 192, d = n - h * 192;
                int trow = bm * 256 + wm2 * 128 + mf * 16 + rg;
                int b = trow >> 11, t = trow & 2047;
                bf16_t* p = out0 + ((size_t)(b * 16 + h) * SEQ + t) * 192 + d;
                #pragma unroll
                for (int rr = 0; rr < 4; ++rr)
                    p[rr * 192] = (bf16_t)acc[mf][nf][rr];
            }
    }
}

// ---------------------------------------------------------------------------
// m97-structure 128x128 GEMM (N=576 kv_a and N=2048 wo), XCD swizzle
// ---------------------------------------------------------------------------
__global__ __launch_bounds__(256)
void gemm_nt(const bf16_t* __restrict__ A, const bf16_t* __restrict__ B,
             float* __restrict__ C, int M, int N, int K, int total, int nbn) {
    __shared__ bf16_t As[4096], Bs[4096];
    int bm, bn;
    xcd_map(blockIdx.x, total, nbn, bm, bn);

    const int tid = threadIdx.x;
    const int lane = tid & 63, w = tid >> 6;
    const int lr = lane & 15, kh = lane >> 4;
    const int wm = (w >> 1) * 64, wn = (w & 1) * 64;
    const int subrow = lane >> 2;
    const int colel = (lane & 3) * 8;

    f32x4 acc[4][4];
    #pragma unroll
    for (int i = 0; i < 4; ++i)
        #pragma unroll
        for (int j = 0; j < 4; ++j) acc[i][j] = 0.0f;

    const int rA = bm * 128 + 32 * w + subrow;
    const int rB = bn * 128 + 32 * w + subrow;
    const int rb1 = (rB < N) ? rB : (N - 1);
    const int rb2 = (rB + 16 < N) ? (rB + 16) : (N - 1);

    for (int kt = 0; kt < K; kt += 32) {
        __syncthreads();
        gload_lds16(A + (size_t)rA * K + kt + colel,        As + (2 * w) * 512);
        gload_lds16(A + (size_t)(rA + 16) * K + kt + colel, As + (2 * w + 1) * 512);
        gload_lds16(B + (size_t)rb1 * K + kt + colel,       Bs + (2 * w) * 512);
        gload_lds16(B + (size_t)rb2 * K + kt + colel,       Bs + (2 * w + 1) * 512);
        __syncthreads();
        bf16x8 af[4], bfr[4];
        #pragma unroll
        for (int im = 0; im < 4; ++im)
            af[im] = *(const bf16x8*)(As + (wm + im * 16 + lr) * 32 + kh * 8);
        #pragma unroll
        for (int jn = 0; jn < 4; ++jn)
            bfr[jn] = *(const bf16x8*)(Bs + (wn + jn * 16 + lr) * 32 + kh * 8);
        #pragma unroll
        for (int im = 0; im < 4; ++im)
            #pragma unroll
            for (int jn = 0; jn < 4; ++jn)
                acc[im][jn] = __builtin_amdgcn_mfma_f32_16x16x32_bf16(
                    af[im], bfr[jn], acc[im][jn], 0, 0, 0);
    }

    const int rg = kh * 4;
    #pragma unroll
    for (int im = 0; im < 4; ++im)
        #pragma unroll
        for (int jn = 0; jn < 4; ++jn) {
            int col = bn * 128 + wn + jn * 16 + lr;
            if (col >= N) continue;
            size_t rowb = (size_t)(bm * 128 + wm + im * 16 + rg);
            #pragma unroll
            for (int rr = 0; rr < 4; ++rr)
                C[(rowb + rr) * N + col] = acc[im][jn][rr];
        }
}

// ---------------------------------------------------------------------------
// Fused: layernorm(kv)->kvnb (bf16), rope(k_pe)->K_pack broadcast,
// rope cos/sin table (b==0 blocks).
// ---------------------------------------------------------------------------
__global__ __launch_bounds__(256)
void rope_ln(const float* __restrict__ kv_all,
             const float* __restrict__ lnw, const float* __restrict__ lnb,
             bf16_t* __restrict__ kvnb, bf16_t* __restrict__ kpack,
             float2* __restrict__ rope_cs, const int* __restrict__ start_pos) {
    const int m = blockIdx.x;
    const int tid = threadIdx.x;
    const int b = m >> 11, t = m & 2047;
    const float pos = (float)(start_pos[0] + t);
    __shared__ float red[8];
    __shared__ float stats[2];
    __shared__ float kbuf[64];

    const float* kvrow = kv_all + (size_t)m * 576;
    float v0 = kvrow[tid], v1 = kvrow[tid + 256];
    float ssum = v0 + v1, ssq = v0 * v0 + v1 * v1;
    for (int off = 32; off > 0; off >>= 1) {
        ssum += __shfl_down(ssum, off);
        ssq  += __shfl_down(ssq, off);
    }
    const int lane = tid & 63, wid = tid >> 6;
    if (lane == 0) { red[wid] = ssum; red[4 + wid] = ssq; }
    __syncthreads();
    if (tid == 0) {
        float ts = red[0] + red[1] + red[2] + red[3];
        float tq = red[4] + red[5] + red[6] + red[7];
        float mu = ts * (1.0f / 512.0f);
        float var = tq * (1.0f / 512.0f) - mu * mu;
        stats[0] = mu;
        stats[1] = rsqrtf(var + LN_EPS);
    }
    if (tid < 32) {
        int j = tid;
        float inv = expf(-(float)j * 0.2878231366242554f);  // 10000^(-j/32)
        float ang = pos * inv;
        float c = cosf(ang), sn = sinf(ang);
        float x1 = kvrow[512 + j], x2 = kvrow[544 + j];
        kbuf[j]      = x1 * c - x2 * sn;
        kbuf[32 + j] = x2 * c + x1 * sn;
        if (b == 0) rope_cs[t * 32 + j] = make_float2(c, sn);
    }
    __syncthreads();
    float mu = stats[0], rstd = stats[1];
    kvnb[(size_t)m * 512 + tid]       = (bf16_t)((v0 - mu) * rstd * lnw[tid] + lnb[tid]);
    kvnb[(size_t)m * 512 + tid + 256] = (bf16_t)((v1 - mu) * rstd * lnw[tid + 256] + lnb[tid + 256]);

    {
        int hh = tid >> 4, j4 = (tid & 15) * 4;
        bf16x4 pk = { (bf16_t)kbuf[j4], (bf16_t)kbuf[j4 + 1],
                      (bf16_t)kbuf[j4 + 2], (bf16_t)kbuf[j4 + 3] };
        *(bf16x4*)(kpack + ((size_t)(b * 16 + hh) * SEQ + t) * 192 + 128 + j4) = pk;
    }
}

// ---------------------------------------------------------------------------
// MFMA flash attention: 1024 single-tile blocks, alternation-balanced
// (each CU's 4 blocks sum to exactly 66 K-steps), single K buffer (48KB LDS
// -> 3 blocks/CU resident), swapped-operand QK^T, swizzled LDS,
// global K/V prefetch hidden under QK+softmax+PV.
// ---------------------------------------------------------------------------
__global__ __launch_bounds__(256, 3)
void attn_mfma(const bf16_t* __restrict__ qb, const bf16_t* __restrict__ kpack,
               const bf16_t* __restrict__ vt, const float2* __restrict__ rope_cs,
               bf16_t* __restrict__ ao) {
    __shared__ bf16_t Ks[64 * 192];     // 24KB
    __shared__ bf16_t Vts[128 * 64];    // 16KB
    __shared__ bf16_t Pls[4 * 16 * 64]; // 8KB, per-wave

    // bid -> (qt, h, b): chunk selects group AND qt direction, so the 4
    // blocks per CU (bid stride 256 -> chunk 0..3, same k) total 66 steps.
    const int bid = blockIdx.x;
    const int xcd = bid & 7, s = bid >> 3;       // s: 0..127
    const int chunk = s >> 5, k = s & 31;
    const int qt = (chunk & 1) ? k : (31 - k);
    const int g = xcd * 4 + chunk;               // group 0..31
    const int h = g & 15, b = g >> 4;

    const int tid = threadIdx.x;
    const int lane = tid & 63, w = tid >> 6;
    const int lr = lane & 15, kh = lane >> 4;
    const int lr7 = lr & 7;
    const int e0 = kh ^ lr7;
    const int e1 = (4 + kh) ^ lr7;
    const size_t bS = (size_t)b * SEQ;
    const bf16_t* kbase = kpack + (size_t)(b * 16 + h) * SEQ * 192;
    const bf16_t* vbase = vt + (size_t)(b * 16 + h) * 128 * SEQ;

    // staging maps
    int kgo_[6], klo_[6], vgo_[4], vlo_[4], vco_[4];
    #pragma unroll
    for (int i = 0; i < 6; ++i) {
        int c = tid + 256 * i;
        int row = c / 24, slot = c % 24;
        kgo_[i] = row * 192 + slot * 8;
        klo_[i] = row * 192 + ((slot & 24) | ((slot ^ row) & 7)) * 8;
    }
    #pragma unroll
    for (int i = 0; i < 4; ++i) {
        int c = tid + 256 * i;
        int row = c >> 3, slot = c & 7;
        vgo_[i] = row;
        vlo_[i] = row * 64 + (slot ^ (row & 7)) * 8;
        vco_[i] = slot;
    }

    const int q0 = qt * 64;
    const int myrow = q0 + w * 16;
    const int qabs = myrow + lr;

    // Q fragments + in-register rope on ks=4/5
    bf16x8 qf[6];
    {
        const bf16_t* qrow = qb + ((size_t)(b * 16 + h) * SEQ + qabs) * 192;
        #pragma unroll
        for (int ks = 0; ks < 6; ++ks)
            qf[ks] = *(const bf16x8*)(qrow + ks * 32 + kh * 8);
        const float2* csp = rope_cs + (size_t)qabs * 32 + kh * 8;
        #pragma unroll
        for (int i = 0; i < 8; ++i) {
            float2 cs = csp[i];
            float x1 = (float)qf[4][i], x2 = (float)qf[5][i];
            qf[4][i] = (bf16_t)(x1 * cs.x - x2 * cs.y);
            qf[5][i] = (bf16_t)(x2 * cs.x + x1 * cs.y);
        }
    }

    f32x4 O[8];
    #pragma unroll
    for (int i = 0; i < 8; ++i) O[i] = 0.0f;
    float m_r = -1e30f, l_r = 0.0f;

    // prologue: K[0], V[0] -> regs
    bf16x8 rkw[6], rkl[6], rv[4];
    #pragma unroll
    for (int i = 0; i < 6; ++i)
        rkw[i] = *(const bf16x8*)(kbase + kgo_[i]);
    #pragma unroll
    for (int i = 0; i < 4; ++i)
        rv[i] = *(const bf16x8*)(vbase + (size_t)vgo_[i] * SEQ + vco_[i] * 8);

    for (int kt = 0; kt <= qt; ++kt) {
        __syncthreads();   // prior step's Ks/Vts reads done -> overwrite safe
        #pragma unroll
        for (int i = 0; i < 6; ++i) *(bf16x8*)(Ks + klo_[i]) = rkw[i];
        #pragma unroll
        for (int i = 0; i < 4; ++i) *(bf16x8*)(Vts + vlo_[i]) = rv[i];
        {
            const int tn = (kt + 1 <= qt ? kt + 1 : qt) * 64;
            #pragma unroll
            for (int i = 0; i < 6; ++i)
                rkl[i] = *(const bf16x8*)(kbase + (size_t)tn * 192 + kgo_[i]);
            #pragma unroll
            for (int i = 0; i < 4; ++i)
                rv[i] = *(const bf16x8*)(vbase + (size_t)vgo_[i] * SEQ + tn + vco_[i] * 8);
        }
        __syncthreads();   // staged tile visible

        // swapped QK^T: D[t][q], q = lr
        f32x4 sacc[4];
        #pragma unroll
        for (int j = 0; j < 4; ++j) sacc[j] = 0.0f;
        __builtin_amdgcn_s_setprio(1);
        #pragma unroll
        for (int ks = 0; ks < 6; ++ks) {
            const int sw = (ks >> 1) * 64 + ((ks & 1) ? e1 : e0) * 8;
            #pragma unroll
            for (int j = 0; j < 4; ++j) {
                bf16x8 kf = *(const bf16x8*)(Ks + (j * 16 + lr) * 192 + sw);
                sacc[j] = __builtin_amdgcn_mfma_f32_16x16x32_bf16(kf, qf[ks], sacc[j], 0, 0, 0);
            }
        }
        __builtin_amdgcn_s_setprio(0);

        const int t0 = kt * 64;
        float p[16];
        if (kt == qt) {
            #pragma unroll
            for (int j = 0; j < 4; ++j)
                #pragma unroll
                for (int rr = 0; rr < 4; ++rr) {
                    int tabs = t0 + j * 16 + kh * 4 + rr;
                    p[j * 4 + rr] = (tabs > qabs) ? -1e30f : sacc[j][rr] * MLA_SCALE;
                }
        } else {
            #pragma unroll
            for (int j = 0; j < 4; ++j)
                #pragma unroll
                for (int rr = 0; rr < 4; ++rr)
                    p[j * 4 + rr] = sacc[j][rr] * MLA_SCALE;
        }

        float mx = p[0];
        #pragma unroll
        for (int e = 1; e < 16; ++e) mx = fmaxf(mx, p[e]);
        mx = fmaxf(mx, __shfl_xor(mx, 16));
        mx = fmaxf(mx, __shfl_xor(mx, 32));

        if (!__all(mx <= m_r + 8.0f)) {
            float mnew = fmaxf(m_r, mx);
            float cr = __expf(m_r - mnew);
            l_r *= cr;
            m_r = mnew;
            float corr[4];
            #pragma unroll
            for (int rr = 0; rr < 4; ++rr)
                corr[rr] = __shfl(cr, kh * 4 + rr);
            #pragma unroll
            for (int dt = 0; dt < 8; ++dt)
                #pragma unroll
                for (int rr = 0; rr < 4; ++rr)
                    O[dt][rr] *= corr[rr];
        }

        float ps = 0.0f;
        #pragma unroll
        for (int e = 0; e < 16; ++e) {
            p[e] = __expf(p[e] - m_r);
            ps += p[e];
        }
        ps += __shfl_xor(ps, 16);
        ps += __shfl_xor(ps, 32);
        l_r += ps;

        // P -> per-wave LDS (swizzled bf16x4); same-wave RAW, no barrier
        bf16_t* pw = Pls + (w * 16 + lr) * 64;
        const int f2 = kh >> 1, h4 = (kh & 1) * 4;
        #pragma unroll
        for (int j = 0; j < 4; ++j) {
            bf16x4 pp = { (bf16_t)p[j * 4], (bf16_t)p[j * 4 + 1],
                          (bf16_t)p[j * 4 + 2], (bf16_t)p[j * 4 + 3] };
            *(bf16x4*)(pw + ((2 * j + f2) ^ lr7) * 8 + h4) = pp;
        }
        bf16x8 pa0 = *(const bf16x8*)(pw + e0 * 8);
        bf16x8 pa1 = *(const bf16x8*)(pw + e1 * 8);
        __builtin_amdgcn_s_setprio(1);
        #pragma unroll
        for (int dt = 0; dt < 8; ++dt) {
            bf16x8 b0 = *(const bf16x8*)(Vts + (dt * 16 + lr) * 64 + e0 * 8);
            O[dt] = __builtin_amdgcn_mfma_f32_16x16x32_bf16(pa0, b0, O[dt], 0, 0, 0);
            bf16x8 b1 = *(const bf16x8*)(Vts + (dt * 16 + lr) * 64 + e1 * 8);
            O[dt] = __builtin_amdgcn_mfma_f32_16x16x32_bf16(pa1, b1, O[dt], 0, 0, 0);
        }
        __builtin_amdgcn_s_setprio(0);
        #pragma unroll
        for (int i = 0; i < 6; ++i) rkw[i] = rkl[i];
    }

    // epilogue
    float linv[4];
    #pragma unroll
    for (int rr = 0; rr < 4; ++rr)
        linv[rr] = 1.0f / __shfl(l_r, kh * 4 + rr);
    #pragma unroll
    for (int rr = 0; rr < 4; ++rr) {
        size_t rowb = (bS + myrow + kh * 4 + rr) * 2048 + h * 128;
        #pragma unroll
        for (int dt = 0; dt < 8; ++dt)
            ao[rowb + dt * 16 + lr] = (bf16_t)(O[dt][rr] * linv[rr]);
    }
}

// ---------------------------------------------------------------------------
extern "C" void kernel_launch(void* const* d_in, const int* in_sizes, int n_in,
                              void* d_out, int out_size, void* d_ws, size_t ws_size,
                              hipStream_t stream) {
    const float* x     = (const float*)d_in[0];
    const float* wq    = (const float*)d_in[1];
    const float* wkv_a = (const float*)d_in[2];
    const float* lnw   = (const float*)d_in[3];
    const float* lnb   = (const float*)d_in[4];
    const float* wkv_b = (const float*)d_in[5];
    const float* wo    = (const float*)d_in[6];
    const int* start_pos = (const int*)d_in[7];
    float* out = (float*)d_out;

    char* w8 = (char*)d_ws;
    bf16_t* xb   = (bf16_t*)(w8);                  // 16777216 B
    bf16_t* wqb  = (bf16_t*)(w8 + 16777216);       // 12582912 B
    bf16_t* wab  = (bf16_t*)(w8 + 29360128);       //  2359296 B
    bf16_t* wbb  = (bf16_t*)(w8 + 31719424);       //  4194304 B
    bf16_t* wob  = (bf16_t*)(w8 + 35913728);       //  8388608 B
    bf16_t* kvnb = (bf16_t*)(w8 + 44302336);       //  4194304 B
    bf16_t* kpk  = (bf16_t*)(w8 + 48496640);       // 25165824 B (K_pack)
    bf16_t* vtb  = (bf16_t*)(w8 + 73662464);       // 16777216 B (Vt)
    bf16_t* aob  = (bf16_t*)(w8 + 90439680);       // 16777216 B
    bf16_t* qbh  = (bf16_t*)(w8 + 107216896);      // 25165824 B (q bf16 head-major)
    float*  kva  = (float*)(w8 + 132382720);       //  9437184 B fp32
    float2* rcs  = (float2*)(w8 + 141819904);      //   524288 B (rope table)

    cvt_all<<<2048, 256, 0, stream>>>(x, wq, wkv_a, wkv_b, wo, xb, wqb, wab, wbb, wob);

    // q = x @ wq.T -> bf16 head-major q[b,h,t,192]
    gemm256<2><<<192, 512, 0, stream>>>(xb, wqb, nullptr, qbh, nullptr, 3072, 2048, 192, 12);
    // kv_all = x @ wkv_a.T (128^2, N=576)
    gemm_nt<<<160, 256, 0, stream>>>(xb, wab, kva, 4096, 576, 2048, 160, 5);
    // layernorm + k_pe rope + rope table
    rope_ln<<<4096, 256, 0, stream>>>(kva, lnw, lnb, kvnb, kpk, rcs, start_pos);
    // k_nope/v -> K_pack/Vt
    gemm256<1><<<256, 512, 0, stream>>>(kvnb, wbb, nullptr, kpk, vtb, 4096, 512, 256, 16);
    // attention (1024 balanced single-tile blocks, 3/CU resident)
    attn_mfma<<<1024, 256, 0, stream>>>(qbh, kpk, vtb, rcs, aob);
    // out = ao @ wo.T (128^2)
    gemm_nt<<<512, 256, 0, stream>>>(aob, wob, out, 4096, 2048, 2048, 512, 16);
}

// Round 12
// 305.378 us; speedup vs baseline: 1.0237x; 1.0237x over previous
//
#include <hip/hip_runtime.h>
#include <hip/hip_bf16.h>
#include <math.h>

typedef __bf16 bf16_t;
typedef __bf16 bf16x2 __attribute__((ext_vector_type(2)));
typedef __bf16 bf16x4 __attribute__((ext_vector_type(4)));
typedef __bf16 bf16x8 __attribute__((ext_vector_type(8)));
typedef float f32x4 __attribute__((ext_vector_type(4)));

#define SEQ 2048
#define MLA_SCALE 0.07216878364870322f
#define LN_EPS 1e-5f

__device__ __forceinline__ void gload_lds16(const bf16_t* g, bf16_t* l) {
    __builtin_amdgcn_global_load_lds(
        (const __attribute__((address_space(1))) uint32_t*)(const void*)g,
        (__attribute__((address_space(3))) uint32_t*)(void*)l, 16, 0, 0);
}

// bijective XCD-aware block swizzle
__device__ __forceinline__ void xcd_map(int bid, int total, int nbn,
                                        int& bm, int& bn) {
    int per = total >> 3;
    int cbm = per / nbn;
    int xcd = bid & 7, s = bid >> 3;
    int q = s / nbn;
    bm = xcd * cbm + q;
    bn = s - q * nbn;
}

// ---------------------------------------------------------------------------
// fused fp32 -> bf16 convert of all 5 buffers (one launch)
// ---------------------------------------------------------------------------
#define CVT_N0 2097152   // x      (float4 units)
#define CVT_N1 1572864   // wq
#define CVT_N2 294912    // wkv_a
#define CVT_N3 524288    // wkv_b
#define CVT_N4 1048576   // wo
#define CVT_TOT (CVT_N0 + CVT_N1 + CVT_N2 + CVT_N3 + CVT_N4)

__global__ __launch_bounds__(256)
void cvt_all(const float* __restrict__ x, const float* __restrict__ wq,
             const float* __restrict__ wa, const float* __restrict__ wb,
             const float* __restrict__ wo, bf16_t* __restrict__ xb,
             bf16_t* __restrict__ wqb, bf16_t* __restrict__ wab,
             bf16_t* __restrict__ wbb, bf16_t* __restrict__ wob) {
    for (int i = blockIdx.x * 256 + threadIdx.x; i < CVT_TOT; i += gridDim.x * 256) {
        const float* src; bf16_t* dst; int off = i;
        if (i < CVT_N0) { src = x; dst = xb; }
        else if (i < CVT_N0 + CVT_N1) { src = wq; dst = wqb; off = i - CVT_N0; }
        else if (i < CVT_N0 + CVT_N1 + CVT_N2) { src = wa; dst = wab; off = i - CVT_N0 - CVT_N1; }
        else if (i < CVT_N0 + CVT_N1 + CVT_N2 + CVT_N3) { src = wb; dst = wbb; off = i - CVT_N0 - CVT_N1 - CVT_N2; }
        else { src = wo; dst = wob; off = i - CVT_N0 - CVT_N1 - CVT_N2 - CVT_N3; }
        float4 v = ((const float4*)src)[off];
        bf16x4 p = { (bf16_t)v.x, (bf16_t)v.y, (bf16_t)v.z, (bf16_t)v.w };
        ((bf16x4*)dst)[off] = p;
    }
}

// ===========================================================================
// 256x256 8-phase GEMM. C[M,N] = A[M,K] * B[N,K]^T, bf16 in, fp32 acc.
// MODE 0: fp32 C.  MODE 1: kvb pack (K_pack + Vt).  MODE 2: q bf16 head-major.
// ===========================================================================
#define G256_PHASE(TAU, KS, MH, HTO, MAT, WAITV)                               \
{                                                                              \
    const int slot_ = (2 * (TAU) + (KS)) & 3;                                  \
    bf16x8 af_[4];                                                             \
    {                                                                          \
        const bf16_t* ab_ = As + slot_ * 8192 +                                \
                            (wm2 * 128 + (MH) * 64 + lr) * 32 + rdcol;         \
        _Pragma("unroll")                                                      \
        for (int f = 0; f < 4; ++f) af_[f] = *(const bf16x8*)(ab_ + f * 512);  \
    }                                                                          \
    if ((MH) == 0) {                                                           \
        const bf16_t* bb_ = Bs + slot_ * 8192 + (wn2 * 64 + lr) * 32 + rdcol;  \
        _Pragma("unroll")                                                      \
        for (int f = 0; f < 4; ++f) bq[f] = *(const bf16x8*)(bb_ + f * 512);   \
    }                                                                          \
    if ((MAT) == 0) stageA(2 * T + 3 + (HTO)); else stageB(2 * T + 3 + (HTO)); \
    __builtin_amdgcn_s_barrier();                                              \
    asm volatile("" ::: "memory");                                             \
    __builtin_amdgcn_s_setprio(1);                                             \
    _Pragma("unroll")                                                          \
    for (int f = 0; f < 4; ++f)                                                \
        _Pragma("unroll")                                                      \
        for (int n = 0; n < 4; ++n)                                            \
            acc[(MH) * 4 + f][n] = __builtin_amdgcn_mfma_f32_16x16x32_bf16(    \
                af_[f], bq[n], acc[(MH) * 4 + f][n], 0, 0, 0);                 \
    __builtin_amdgcn_s_setprio(0);                                             \
    asm volatile("" ::: "memory");                                             \
    if (WAITV) asm volatile("s_waitcnt vmcnt(8)" ::: "memory");                \
    __builtin_amdgcn_s_barrier();                                              \
}

template<int MODE>
__global__ __launch_bounds__(512, 2)
void gemm256(const bf16_t* __restrict__ A, const bf16_t* __restrict__ B,
             float* __restrict__ C, bf16_t* __restrict__ out0,
             bf16_t* __restrict__ out1, int N, int K, int total, int nbn) {
    __shared__ __attribute__((aligned(16))) bf16_t As[32768];
    __shared__ __attribute__((aligned(16))) bf16_t Bs[32768];
    __shared__ __attribute__((aligned(16))) bf16_t Ds[8192];

    const int tid = threadIdx.x;
    const int lane = tid & 63, w = tid >> 6;
    const int lr = lane & 15, kh = lane >> 4;
    const int wm2 = w >> 2, wn2 = w & 3;
    int bm, bn;
    xcd_map(blockIdx.x, total, nbn, bm, bn);
    const int NT = K >> 6;

    const int rdcol = 8 * (kh ^ ((lr >> 1) & 3));
    const int strow = (w << 5) + (lane >> 2);
    const int scol = 8 * ((lane & 3) ^ ((lane >> 3) & 3));

    f32x4 acc[8][4];
    #pragma unroll
    for (int i = 0; i < 8; ++i)
        #pragma unroll
        for (int j = 0; j < 4; ++j) acc[i][j] = 0.0f;

    auto stageA = [&](int ht) {
        int hs = (ht < 2 * NT) ? ht : (2 * NT - 1);
        int tau = hs >> 1, kap = hs & 1;
        const bf16_t* g = A + (size_t)(bm * 256 + strow) * K + tau * 64 + kap * 32 + scol;
        bf16_t* l = (ht < 2 * NT) ? (As + (ht & 3) * 8192 + w * 1024) : (Ds + w * 1024);
        gload_lds16(g, l);
        gload_lds16(g + (size_t)16 * K, l + 512);
    };
    auto stageB = [&](int ht) {
        int hs = (ht < 2 * NT) ? ht : (2 * NT - 1);
        int tau = hs >> 1, kap = hs & 1;
        const bf16_t* g = B + (size_t)(bn * 256 + strow) * K + tau * 64 + kap * 32 + scol;
        bf16_t* l = (ht < 2 * NT) ? (Bs + (ht & 3) * 8192 + w * 1024) : (Ds + w * 1024);
        gload_lds16(g, l);
        gload_lds16(g + (size_t)16 * K, l + 512);
    };

    stageA(0); stageB(0); stageA(1); stageB(1); stageA(2); stageB(2);
    asm volatile("s_waitcnt vmcnt(8)" ::: "memory");
    __builtin_amdgcn_s_barrier();

    for (int it = 0; it < (NT >> 1); ++it) {
        const int T = 2 * it;
        bf16x8 bq[4];
        G256_PHASE(T,     0, 0, 0, 0, 0)
        G256_PHASE(T,     0, 1, 0, 1, 1)
        G256_PHASE(T,     1, 0, 1, 0, 0)
        G256_PHASE(T,     1, 1, 1, 1, 1)
        G256_PHASE(T + 1, 0, 0, 2, 0, 0)
        G256_PHASE(T + 1, 0, 1, 2, 1, 1)
        G256_PHASE(T + 1, 1, 0, 3, 0, 0)
        G256_PHASE(T + 1, 1, 1, 3, 1, 1)
    }

    const int rg = kh * 4;
    if (MODE == 0) {
        #pragma unroll
        for (int mf = 0; mf < 8; ++mf)
            #pragma unroll
            for (int nf = 0; nf < 4; ++nf) {
                size_t row0 = (size_t)(bm * 256 + wm2 * 128 + mf * 16 + rg);
                int col = bn * 256 + wn2 * 64 + nf * 16 + lr;
                #pragma unroll
                for (int rr = 0; rr < 4; ++rr)
                    C[(row0 + rr) * N + col] = acc[mf][nf][rr];
            }
    } else if (MODE == 1) {
        const int h = bn;
        #pragma unroll
        for (int mf = 0; mf < 8; ++mf)
            #pragma unroll
            for (int nf = 0; nf < 4; ++nf) {
                int d = wn2 * 64 + nf * 16 + lr;
                int trow = bm * 256 + wm2 * 128 + mf * 16 + rg;
                int b = trow >> 11, t = trow & 2047;
                if (d < 128) {
                    bf16_t* p = out0 + ((size_t)(b * 16 + h) * SEQ + t) * 192 + d;
                    #pragma unroll
                    for (int rr = 0; rr < 4; ++rr)
                        p[rr * 192] = (bf16_t)acc[mf][nf][rr];
                } else {
                    bf16x4 pv = { (bf16_t)acc[mf][nf][0], (bf16_t)acc[mf][nf][1],
                                  (bf16_t)acc[mf][nf][2], (bf16_t)acc[mf][nf][3] };
                    *(bf16x4*)(out1 + ((size_t)(b * 16 + h) * 128 + (d - 128)) * SEQ + t) = pv;
                }
            }
    } else {
        #pragma unroll
        for (int mf = 0; mf < 8; ++mf)
            #pragma unroll
            for (int nf = 0; nf < 4; ++nf) {
                int n = bn * 256 + wn2 * 64 + nf * 16 + lr;
                int h = n / 192, d = n - h * 192;
                int trow = bm * 256 + wm2 * 128 + mf * 16 + rg;
                int b = trow >> 11, t = trow & 2047;
                bf16_t* p = out0 + ((size_t)(b * 16 + h) * SEQ + t) * 192 + d;
                #pragma unroll
                for (int rr = 0; rr < 4; ++rr)
                    p[rr * 192] = (bf16_t)acc[mf][nf][rr];
            }
    }
}

// ---------------------------------------------------------------------------
// m97-structure 128x128 GEMM (N=576 kv_a and N=2048 wo), XCD swizzle
// ---------------------------------------------------------------------------
__global__ __launch_bounds__(256)
void gemm_nt(const bf16_t* __restrict__ A, const bf16_t* __restrict__ B,
             float* __restrict__ C, int M, int N, int K, int total, int nbn) {
    __shared__ bf16_t As[4096], Bs[4096];
    int bm, bn;
    xcd_map(blockIdx.x, total, nbn, bm, bn);

    const int tid = threadIdx.x;
    const int lane = tid & 63, w = tid >> 6;
    const int lr = lane & 15, kh = lane >> 4;
    const int wm = (w >> 1) * 64, wn = (w & 1) * 64;
    const int subrow = lane >> 2;
    const int colel = (lane & 3) * 8;

    f32x4 acc[4][4];
    #pragma unroll
    for (int i = 0; i < 4; ++i)
        #pragma unroll
        for (int j = 0; j < 4; ++j) acc[i][j] = 0.0f;

    const int rA = bm * 128 + 32 * w + subrow;
    const int rB = bn * 128 + 32 * w + subrow;
    const int rb1 = (rB < N) ? rB : (N - 1);
    const int rb2 = (rB + 16 < N) ? (rB + 16) : (N - 1);

    for (int kt = 0; kt < K; kt += 32) {
        __syncthreads();
        gload_lds16(A + (size_t)rA * K + kt + colel,        As + (2 * w) * 512);
        gload_lds16(A + (size_t)(rA + 16) * K + kt + colel, As + (2 * w + 1) * 512);
        gload_lds16(B + (size_t)rb1 * K + kt + colel,       Bs + (2 * w) * 512);
        gload_lds16(B + (size_t)rb2 * K + kt + colel,       Bs + (2 * w + 1) * 512);
        __syncthreads();
        bf16x8 af[4], bfr[4];
        #pragma unroll
        for (int im = 0; im < 4; ++im)
            af[im] = *(const bf16x8*)(As + (wm + im * 16 + lr) * 32 + kh * 8);
        #pragma unroll
        for (int jn = 0; jn < 4; ++jn)
            bfr[jn] = *(const bf16x8*)(Bs + (wn + jn * 16 + lr) * 32 + kh * 8);
        #pragma unroll
        for (int im = 0; im < 4; ++im)
            #pragma unroll
            for (int jn = 0; jn < 4; ++jn)
                acc[im][jn] = __builtin_amdgcn_mfma_f32_16x16x32_bf16(
                    af[im], bfr[jn], acc[im][jn], 0, 0, 0);
    }

    const int rg = kh * 4;
    #pragma unroll
    for (int im = 0; im < 4; ++im)
        #pragma unroll
        for (int jn = 0; jn < 4; ++jn) {
            int col = bn * 128 + wn + jn * 16 + lr;
            if (col >= N) continue;
            size_t rowb = (size_t)(bm * 128 + wm + im * 16 + rg);
            #pragma unroll
            for (int rr = 0; rr < 4; ++rr)
                C[(rowb + rr) * N + col] = acc[im][jn][rr];
        }
}

// ---------------------------------------------------------------------------
// Fused: layernorm(kv)->kvnb (bf16), rope(k_pe)->K_pack broadcast,
// rope cos/sin table (b==0 blocks).
// ---------------------------------------------------------------------------
__global__ __launch_bounds__(256)
void rope_ln(const float* __restrict__ kv_all,
             const float* __restrict__ lnw, const float* __restrict__ lnb,
             bf16_t* __restrict__ kvnb, bf16_t* __restrict__ kpack,
             float2* __restrict__ rope_cs, const int* __restrict__ start_pos) {
    const int m = blockIdx.x;
    const int tid = threadIdx.x;
    const int b = m >> 11, t = m & 2047;
    const float pos = (float)(start_pos[0] + t);
    __shared__ float red[8];
    __shared__ float stats[2];
    __shared__ float kbuf[64];

    const float* kvrow = kv_all + (size_t)m * 576;
    float v0 = kvrow[tid], v1 = kvrow[tid + 256];
    float ssum = v0 + v1, ssq = v0 * v0 + v1 * v1;
    for (int off = 32; off > 0; off >>= 1) {
        ssum += __shfl_down(ssum, off);
        ssq  += __shfl_down(ssq, off);
    }
    const int lane = tid & 63, wid = tid >> 6;
    if (lane == 0) { red[wid] = ssum; red[4 + wid] = ssq; }
    __syncthreads();
    if (tid == 0) {
        float ts = red[0] + red[1] + red[2] + red[3];
        float tq = red[4] + red[5] + red[6] + red[7];
        float mu = ts * (1.0f / 512.0f);
        float var = tq * (1.0f / 512.0f) - mu * mu;
        stats[0] = mu;
        stats[1] = rsqrtf(var + LN_EPS);
    }
    if (tid < 32) {
        int j = tid;
        float inv = expf(-(float)j * 0.2878231366242554f);  // 10000^(-j/32)
        float ang = pos * inv;
        float c = cosf(ang), sn = sinf(ang);
        float x1 = kvrow[512 + j], x2 = kvrow[544 + j];
        kbuf[j]      = x1 * c - x2 * sn;
        kbuf[32 + j] = x2 * c + x1 * sn;
        if (b == 0) rope_cs[t * 32 + j] = make_float2(c, sn);
    }
    __syncthreads();
    float mu = stats[0], rstd = stats[1];
    kvnb[(size_t)m * 512 + tid]       = (bf16_t)((v0 - mu) * rstd * lnw[tid] + lnb[tid]);
    kvnb[(size_t)m * 512 + tid + 256] = (bf16_t)((v1 - mu) * rstd * lnw[tid + 256] + lnb[tid + 256]);

    {
        int hh = tid >> 4, j4 = (tid & 15) * 4;
        bf16x4 pk = { (bf16_t)kbuf[j4], (bf16_t)kbuf[j4 + 1],
                      (bf16_t)kbuf[j4 + 2], (bf16_t)kbuf[j4 + 3] };
        *(bf16x4*)(kpack + ((size_t)(b * 16 + hh) * SEQ + t) * 192 + 128 + j4) = pk;
    }
}

// ---------------------------------------------------------------------------
// MFMA flash attention v2: 512 paired blocks {31-bx,bx} (33 steps each),
// 128 threads = 2 waves, each wave owns 32 q rows (2 q-groups sharing all
// K/V LDS reads -> LDS traffic per q-row halved). K/V staged direct via
// global_load_lds with swizzle-inverted SOURCE addresses (linear LDS dest).
// K double-buffered; counted vmcnt(12) lets K-prefetch fly across barrier.
// LDS 72KB -> 2 blocks/CU.
// ---------------------------------------------------------------------------
__global__ __launch_bounds__(128)
void attn_mfma(const bf16_t* __restrict__ qb, const bf16_t* __restrict__ kpack,
               const bf16_t* __restrict__ vt, const float2* __restrict__ rope_cs,
               bf16_t* __restrict__ ao) {
    __shared__ __attribute__((aligned(16))) bf16_t Ks[2][64 * 192]; // 48KB
    __shared__ __attribute__((aligned(16))) bf16_t Vts[128 * 64];   // 16KB
    __shared__ __attribute__((aligned(16))) bf16_t Pls[2 * 32 * 64];// 8KB

    const int bid = blockIdx.x;
    const int xcd = bid & 7, s = bid >> 3;       // s: 0..63
    const int grp = xcd * 4 + (s >> 4);          // group 0..31
    const int bx = s & 15;
    const int h = grp & 15, b = grp >> 4;

    const int tid = threadIdx.x;                 // 0..127
    const int lane = tid & 63, w = tid >> 6;     // w: 0..1
    const int lr = lane & 15, kh = lane >> 4;
    const int lr7 = lr & 7;
    const int e0 = kh ^ lr7;
    const int e1 = (4 + kh) ^ lr7;
    const size_t bS = (size_t)b * SEQ;
    const bf16_t* kbase = kpack + (size_t)(b * 16 + h) * SEQ * 192;
    const bf16_t* vbase = vt + (size_t)(b * 16 + h) * 128 * SEQ;

    // K staging: 12 gload_lds/thread covering 24KB; LDS dest is linear
    // (pos c = tid + 128*i); source slot is the swizzle involution of the
    // linear slot so that swizzled READS return original data.
    int kgo_[12];
    #pragma unroll
    for (int i = 0; i < 12; ++i) {
        int c = tid + 128 * i;
        int row = c / 24, sl = c % 24;
        kgo_[i] = row * 192 + ((sl & 24) | ((sl ^ row) & 7)) * 8;
    }
    // V staging: 8 gload_lds/thread covering 16KB
    int vgo_[8];
    #pragma unroll
    for (int i = 0; i < 8; ++i) {
        int c = tid + 128 * i;
        int d = c >> 3, sl = c & 7;
        vgo_[i] = d * SEQ + ((sl ^ (d & 7)) * 8);
    }

    for (int half = 0; half < 2; ++half) {
        const int qt = half ? bx : (31 - bx);
        const int q0 = qt * 64;
        // wave w owns rows q0 + w*32 .. +32, as 2 groups of 16
        int qabs[2];
        qabs[0] = q0 + w * 32 + lr;
        qabs[1] = q0 + w * 32 + 16 + lr;

        // Q fragments (bf16) + in-register rope on ks=4/5
        bf16x8 qf[2][6];
        #pragma unroll
        for (int g = 0; g < 2; ++g) {
            const bf16_t* qrow = qb + ((size_t)(b * 16 + h) * SEQ + qabs[g]) * 192;
            #pragma unroll
            for (int ks = 0; ks < 6; ++ks)
                qf[g][ks] = *(const bf16x8*)(qrow + ks * 32 + kh * 8);
            const float2* csp = rope_cs + (size_t)qabs[g] * 32 + kh * 8;
            #pragma unroll
            for (int i = 0; i < 8; ++i) {
                float2 cs = csp[i];
                float x1 = (float)qf[g][4][i], x2 = (float)qf[g][5][i];
                qf[g][4][i] = (bf16_t)(x1 * cs.x - x2 * cs.y);
                qf[g][5][i] = (bf16_t)(x2 * cs.x + x1 * cs.y);
            }
        }

        f32x4 O[2][8];
        #pragma unroll
        for (int g = 0; g < 2; ++g)
            #pragma unroll
            for (int i = 0; i < 8; ++i) O[g][i] = 0.0f;
        float m_r[2] = { -1e30f, -1e30f }, l_r[2] = { 0.0f, 0.0f };

        int cur = 0;
        // prologue: K[0] -> Ks[0]
        #pragma unroll
        for (int i = 0; i < 12; ++i)
            gload_lds16(kbase + kgo_[i], Ks[0] + (128 * i + 64 * w) * 8);
        asm volatile("s_waitcnt vmcnt(0)" ::: "memory");
        __syncthreads();

        for (int kt = 0; kt <= qt; ++kt) {
            bf16_t* kcur = Ks[cur];
            bf16_t* knxt = Ks[cur ^ 1];
            // issue V[kt] -> Vts (landed by vmcnt(12) below)
            #pragma unroll
            for (int i = 0; i < 8; ++i)
                gload_lds16(vbase + vgo_[i] + kt * 64, Vts + (128 * i + 64 * w) * 8);
            // issue K[kt+1] -> Ks[cur^1] (lands by step end vmcnt(0))
            const int tn = (kt + 1 <= qt) ? (kt + 1) : qt;
            #pragma unroll
            for (int i = 0; i < 12; ++i)
                gload_lds16(kbase + (size_t)tn * 12288 + kgo_[i],
                            knxt + (128 * i + 64 * w) * 8);

            // swapped QK^T: D[t][q]; each kf read serves BOTH q-groups
            f32x4 sacc[2][4];
            #pragma unroll
            for (int g = 0; g < 2; ++g)
                #pragma unroll
                for (int j = 0; j < 4; ++j) sacc[g][j] = 0.0f;
            __builtin_amdgcn_s_setprio(1);
            #pragma unroll
            for (int ks = 0; ks < 6; ++ks) {
                const int sw = (ks >> 1) * 64 + ((ks & 1) ? e1 : e0) * 8;
                #pragma unroll
                for (int j = 0; j < 4; ++j) {
                    bf16x8 kf = *(const bf16x8*)(kcur + (j * 16 + lr) * 192 + sw);
                    sacc[0][j] = __builtin_amdgcn_mfma_f32_16x16x32_bf16(kf, qf[0][ks], sacc[0][j], 0, 0, 0);
                    sacc[1][j] = __builtin_amdgcn_mfma_f32_16x16x32_bf16(kf, qf[1][ks], sacc[1][j], 0, 0, 0);
                }
            }
            __builtin_amdgcn_s_setprio(0);

            const int t0 = kt * 64;
            const int f2 = kh >> 1, h4 = (kh & 1) * 4;
            #pragma unroll
            for (int g = 0; g < 2; ++g) {
                float p[16];
                if (kt == qt) {
                    #pragma unroll
                    for (int j = 0; j < 4; ++j)
                        #pragma unroll
                        for (int rr = 0; rr < 4; ++rr) {
                            int tabs = t0 + j * 16 + kh * 4 + rr;
                            p[j * 4 + rr] = (tabs > qabs[g]) ? -1e30f
                                           : sacc[g][j][rr] * MLA_SCALE;
                        }
                } else {
                    #pragma unroll
                    for (int j = 0; j < 4; ++j)
                        #pragma unroll
                        for (int rr = 0; rr < 4; ++rr)
                            p[j * 4 + rr] = sacc[g][j][rr] * MLA_SCALE;
                }

                float mx = p[0];
                #pragma unroll
                for (int e = 1; e < 16; ++e) mx = fmaxf(mx, p[e]);
                mx = fmaxf(mx, __shfl_xor(mx, 16));
                mx = fmaxf(mx, __shfl_xor(mx, 32));

                if (!__all(mx <= m_r[g] + 8.0f)) {   // T13 defer-max
                    float mnew = fmaxf(m_r[g], mx);
                    float cr = __expf(m_r[g] - mnew);
                    l_r[g] *= cr;
                    m_r[g] = mnew;
                    float corr[4];
                    #pragma unroll
                    for (int rr = 0; rr < 4; ++rr)
                        corr[rr] = __shfl(cr, kh * 4 + rr);
                    #pragma unroll
                    for (int dt = 0; dt < 8; ++dt)
                        #pragma unroll
                        for (int rr = 0; rr < 4; ++rr)
                            O[g][dt][rr] *= corr[rr];
                }

                float ps = 0.0f;
                #pragma unroll
                for (int e = 0; e < 16; ++e) {
                    p[e] = __expf(p[e] - m_r[g]);
                    ps += p[e];
                }
                ps += __shfl_xor(ps, 16);
                ps += __shfl_xor(ps, 32);
                l_r[g] += ps;

                bf16_t* pw = Pls + (w * 32 + g * 16 + lr) * 64;
                #pragma unroll
                for (int j = 0; j < 4; ++j) {
                    bf16x4 pp = { (bf16_t)p[j * 4], (bf16_t)p[j * 4 + 1],
                                  (bf16_t)p[j * 4 + 2], (bf16_t)p[j * 4 + 3] };
                    *(bf16x4*)(pw + ((2 * j + f2) ^ lr7) * 8 + h4) = pp;
                }
            }

            asm volatile("s_waitcnt vmcnt(12)" ::: "memory");  // V landed; K still flying
            __syncthreads();

            // PV: V fragments read once, used by both q-groups
            bf16x8 pa[2][2];
            #pragma unroll
            for (int g = 0; g < 2; ++g) {
                const bf16_t* pw = Pls + (w * 32 + g * 16 + lr) * 64;
                pa[g][0] = *(const bf16x8*)(pw + e0 * 8);
                pa[g][1] = *(const bf16x8*)(pw + e1 * 8);
            }
            __builtin_amdgcn_s_setprio(1);
            #pragma unroll
            for (int dt = 0; dt < 8; ++dt) {
                bf16x8 b0 = *(const bf16x8*)(Vts + (dt * 16 + lr) * 64 + e0 * 8);
                bf16x8 b1 = *(const bf16x8*)(Vts + (dt * 16 + lr) * 64 + e1 * 8);
                O[0][dt] = __builtin_amdgcn_mfma_f32_16x16x32_bf16(pa[0][0], b0, O[0][dt], 0, 0, 0);
                O[0][dt] = __builtin_amdgcn_mfma_f32_16x16x32_bf16(pa[0][1], b1, O[0][dt], 0, 0, 0);
                O[1][dt] = __builtin_amdgcn_mfma_f32_16x16x32_bf16(pa[1][0], b0, O[1][dt], 0, 0, 0);
                O[1][dt] = __builtin_amdgcn_mfma_f32_16x16x32_bf16(pa[1][1], b1, O[1][dt], 0, 0, 0);
            }
            __builtin_amdgcn_s_setprio(0);

            asm volatile("s_waitcnt vmcnt(0)" ::: "memory");   // K[kt+1] landed
            __syncthreads();                                    // visible; Vts free
            cur ^= 1;
        }

        // epilogue
        #pragma unroll
        for (int g = 0; g < 2; ++g) {
            float linv[4];
            #pragma unroll
            for (int rr = 0; rr < 4; ++rr)
                linv[rr] = 1.0f / __shfl(l_r[g], kh * 4 + rr);
            #pragma unroll
            for (int rr = 0; rr < 4; ++rr) {
                size_t rowb = (bS + q0 + w * 32 + g * 16 + kh * 4 + rr) * 2048 + h * 128;
                #pragma unroll
                for (int dt = 0; dt < 8; ++dt)
                    ao[rowb + dt * 16 + lr] = (bf16_t)(O[g][dt][rr] * linv[rr]);
            }
        }
        __syncthreads();
    }
}

// ---------------------------------------------------------------------------
extern "C" void kernel_launch(void* const* d_in, const int* in_sizes, int n_in,
                              void* d_out, int out_size, void* d_ws, size_t ws_size,
                              hipStream_t stream) {
    const float* x     = (const float*)d_in[0];
    const float* wq    = (const float*)d_in[1];
    const float* wkv_a = (const float*)d_in[2];
    const float* lnw   = (const float*)d_in[3];
    const float* lnb   = (const float*)d_in[4];
    const float* wkv_b = (const float*)d_in[5];
    const float* wo    = (const float*)d_in[6];
    const int* start_pos = (const int*)d_in[7];
    float* out = (float*)d_out;

    char* w8 = (char*)d_ws;
    bf16_t* xb   = (bf16_t*)(w8);                  // 16777216 B
    bf16_t* wqb  = (bf16_t*)(w8 + 16777216);       // 12582912 B
    bf16_t* wab  = (bf16_t*)(w8 + 29360128);       //  2359296 B
    bf16_t* wbb  = (bf16_t*)(w8 + 31719424);       //  4194304 B
    bf16_t* wob  = (bf16_t*)(w8 + 35913728);       //  8388608 B
    bf16_t* kvnb = (bf16_t*)(w8 + 44302336);       //  4194304 B
    bf16_t* kpk  = (bf16_t*)(w8 + 48496640);       // 25165824 B (K_pack)
    bf16_t* vtb  = (bf16_t*)(w8 + 73662464);       // 16777216 B (Vt)
    bf16_t* aob  = (bf16_t*)(w8 + 90439680);       // 16777216 B
    bf16_t* qbh  = (bf16_t*)(w8 + 107216896);      // 25165824 B (q bf16 head-major)
    float*  kva  = (float*)(w8 + 132382720);       //  9437184 B fp32
    float2* rcs  = (float2*)(w8 + 141819904);      //   524288 B (rope table)

    cvt_all<<<2048, 256, 0, stream>>>(x, wq, wkv_a, wkv_b, wo, xb, wqb, wab, wbb, wob);

    // q = x @ wq.T -> bf16 head-major q[b,h,t,192]
    gemm256<2><<<192, 512, 0, stream>>>(xb, wqb, nullptr, qbh, nullptr, 3072, 2048, 192, 12);
    // kv_all = x @ wkv_a.T (128^2, N=576)
    gemm_nt<<<160, 256, 0, stream>>>(xb, wab, kva, 4096, 576, 2048, 160, 5);
    // layernorm + k_pe rope + rope table
    rope_ln<<<4096, 256, 0, stream>>>(kva, lnw, lnb, kvnb, kpk, rcs, start_pos);
    // k_nope/v -> K_pack/Vt
    gemm256<1><<<256, 512, 0, stream>>>(kvnb, wbb, nullptr, kpk, vtb, 4096, 512, 256, 16);
    // attention (512 paired blocks, 128 threads, 2 q-groups/wave)
    attn_mfma<<<512, 128, 0, stream>>>(qbh, kpk, vtb, rcs, aob);
    // out = ao @ wo.T (128^2)
    gemm_nt<<<512, 256, 0, stream>>>(aob, wob, out, 4096, 2048, 2048, 512, 16);
}

// Round 13
// 285.188 us; speedup vs baseline: 1.0962x; 1.0708x over previous
//
#include <hip/hip_runtime.h>
#include <hip/hip_bf16.h>
#include <math.h>

typedef __bf16 bf16_t;
typedef __bf16 bf16x2 __attribute__((ext_vector_type(2)));
typedef __bf16 bf16x4 __attribute__((ext_vector_type(4)));
typedef __bf16 bf16x8 __attribute__((ext_vector_type(8)));
typedef float f32x4 __attribute__((ext_vector_type(4)));

#define SEQ 2048
#define MLA_SCALE 0.07216878364870322f
#define LN_EPS 1e-5f

__device__ __forceinline__ void gload_lds16(const bf16_t* g, bf16_t* l) {
    __builtin_amdgcn_global_load_lds(
        (const __attribute__((address_space(1))) uint32_t*)(const void*)g,
        (__attribute__((address_space(3))) uint32_t*)(void*)l, 16, 0, 0);
}

// bijective XCD-aware block swizzle
__device__ __forceinline__ void xcd_map(int bid, int total, int nbn,
                                        int& bm, int& bn) {
    int per = total >> 3;
    int cbm = per / nbn;
    int xcd = bid & 7, s = bid >> 3;
    int q = s / nbn;
    bm = xcd * cbm + q;
    bn = s - q * nbn;
}

// ---------------------------------------------------------------------------
// fused fp32 -> bf16 convert of all 5 buffers (one launch)
// ---------------------------------------------------------------------------
#define CVT_N0 2097152   // x      (float4 units)
#define CVT_N1 1572864   // wq
#define CVT_N2 294912    // wkv_a
#define CVT_N3 524288    // wkv_b
#define CVT_N4 1048576   // wo
#define CVT_TOT (CVT_N0 + CVT_N1 + CVT_N2 + CVT_N3 + CVT_N4)

__global__ __launch_bounds__(256)
void cvt_all(const float* __restrict__ x, const float* __restrict__ wq,
             const float* __restrict__ wa, const float* __restrict__ wb,
             const float* __restrict__ wo, bf16_t* __restrict__ xb,
             bf16_t* __restrict__ wqb, bf16_t* __restrict__ wab,
             bf16_t* __restrict__ wbb, bf16_t* __restrict__ wob) {
    for (int i = blockIdx.x * 256 + threadIdx.x; i < CVT_TOT; i += gridDim.x * 256) {
        const float* src; bf16_t* dst; int off = i;
        if (i < CVT_N0) { src = x; dst = xb; }
        else if (i < CVT_N0 + CVT_N1) { src = wq; dst = wqb; off = i - CVT_N0; }
        else if (i < CVT_N0 + CVT_N1 + CVT_N2) { src = wa; dst = wab; off = i - CVT_N0 - CVT_N1; }
        else if (i < CVT_N0 + CVT_N1 + CVT_N2 + CVT_N3) { src = wb; dst = wbb; off = i - CVT_N0 - CVT_N1 - CVT_N2; }
        else { src = wo; dst = wob; off = i - CVT_N0 - CVT_N1 - CVT_N2 - CVT_N3; }
        float4 v = ((const float4*)src)[off];
        bf16x4 p = { (bf16_t)v.x, (bf16_t)v.y, (bf16_t)v.z, (bf16_t)v.w };
        ((bf16x4*)dst)[off] = p;
    }
}

// ===========================================================================
// 256x256 8-phase GEMM. C[M,N] = A[M,K] * B[N,K]^T, bf16 in, fp32 acc.
// MODE 0: fp32 C.  MODE 1: kvb pack (K_pack + Vt).  MODE 2: q bf16 head-major.
// ===========================================================================
#define G256_PHASE(TAU, KS, MH, HTO, MAT, WAITV)                               \
{                                                                              \
    const int slot_ = (2 * (TAU) + (KS)) & 3;                                  \
    bf16x8 af_[4];                                                             \
    {                                                                          \
        const bf16_t* ab_ = As + slot_ * 8192 +                                \
                            (wm2 * 128 + (MH) * 64 + lr) * 32 + rdcol;         \
        _Pragma("unroll")                                                      \
        for (int f = 0; f < 4; ++f) af_[f] = *(const bf16x8*)(ab_ + f * 512);  \
    }                                                                          \
    if ((MH) == 0) {                                                           \
        const bf16_t* bb_ = Bs + slot_ * 8192 + (wn2 * 64 + lr) * 32 + rdcol;  \
        _Pragma("unroll")                                                      \
        for (int f = 0; f < 4; ++f) bq[f] = *(const bf16x8*)(bb_ + f * 512);   \
    }                                                                          \
    if ((MAT) == 0) stageA(2 * T + 3 + (HTO)); else stageB(2 * T + 3 + (HTO)); \
    __builtin_amdgcn_s_barrier();                                              \
    asm volatile("" ::: "memory");                                             \
    __builtin_amdgcn_s_setprio(1);                                             \
    _Pragma("unroll")                                                          \
    for (int f = 0; f < 4; ++f)                                                \
        _Pragma("unroll")                                                      \
        for (int n = 0; n < 4; ++n)                                            \
            acc[(MH) * 4 + f][n] = __builtin_amdgcn_mfma_f32_16x16x32_bf16(    \
                af_[f], bq[n], acc[(MH) * 4 + f][n], 0, 0, 0);                 \
    __builtin_amdgcn_s_setprio(0);                                             \
    asm volatile("" ::: "memory");                                             \
    if (WAITV) asm volatile("s_waitcnt vmcnt(8)" ::: "memory");                \
    __builtin_amdgcn_s_barrier();                                              \
}

template<int MODE>
__global__ __launch_bounds__(512, 2)
void gemm256(const bf16_t* __restrict__ A, const bf16_t* __restrict__ B,
             float* __restrict__ C, bf16_t* __restrict__ out0,
             bf16_t* __restrict__ out1, int N, int K, int total, int nbn) {
    __shared__ __attribute__((aligned(16))) bf16_t As[32768];
    __shared__ __attribute__((aligned(16))) bf16_t Bs[32768];
    __shared__ __attribute__((aligned(16))) bf16_t Ds[8192];

    const int tid = threadIdx.x;
    const int lane = tid & 63, w = tid >> 6;
    const int lr = lane & 15, kh = lane >> 4;
    const int wm2 = w >> 2, wn2 = w & 3;
    int bm, bn;
    xcd_map(blockIdx.x, total, nbn, bm, bn);
    const int NT = K >> 6;

    const int rdcol = 8 * (kh ^ ((lr >> 1) & 3));
    const int strow = (w << 5) + (lane >> 2);
    const int scol = 8 * ((lane & 3) ^ ((lane >> 3) & 3));

    f32x4 acc[8][4];
    #pragma unroll
    for (int i = 0; i < 8; ++i)
        #pragma unroll
        for (int j = 0; j < 4; ++j) acc[i][j] = 0.0f;

    auto stageA = [&](int ht) {
        int hs = (ht < 2 * NT) ? ht : (2 * NT - 1);
        int tau = hs >> 1, kap = hs & 1;
        const bf16_t* g = A + (size_t)(bm * 256 + strow) * K + tau * 64 + kap * 32 + scol;
        bf16_t* l = (ht < 2 * NT) ? (As + (ht & 3) * 8192 + w * 1024) : (Ds + w * 1024);
        gload_lds16(g, l);
        gload_lds16(g + (size_t)16 * K, l + 512);
    };
    auto stageB = [&](int ht) {
        int hs = (ht < 2 * NT) ? ht : (2 * NT - 1);
        int tau = hs >> 1, kap = hs & 1;
        const bf16_t* g = B + (size_t)(bn * 256 + strow) * K + tau * 64 + kap * 32 + scol;
        bf16_t* l = (ht < 2 * NT) ? (Bs + (ht & 3) * 8192 + w * 1024) : (Ds + w * 1024);
        gload_lds16(g, l);
        gload_lds16(g + (size_t)16 * K, l + 512);
    };

    stageA(0); stageB(0); stageA(1); stageB(1); stageA(2); stageB(2);
    asm volatile("s_waitcnt vmcnt(8)" ::: "memory");
    __builtin_amdgcn_s_barrier();

    for (int it = 0; it < (NT >> 1); ++it) {
        const int T = 2 * it;
        bf16x8 bq[4];
        G256_PHASE(T,     0, 0, 0, 0, 0)
        G256_PHASE(T,     0, 1, 0, 1, 1)
        G256_PHASE(T,     1, 0, 1, 0, 0)
        G256_PHASE(T,     1, 1, 1, 1, 1)
        G256_PHASE(T + 1, 0, 0, 2, 0, 0)
        G256_PHASE(T + 1, 0, 1, 2, 1, 1)
        G256_PHASE(T + 1, 1, 0, 3, 0, 0)
        G256_PHASE(T + 1, 1, 1, 3, 1, 1)
    }

    const int rg = kh * 4;
    if (MODE == 0) {
        #pragma unroll
        for (int mf = 0; mf < 8; ++mf)
            #pragma unroll
            for (int nf = 0; nf < 4; ++nf) {
                size_t row0 = (size_t)(bm * 256 + wm2 * 128 + mf * 16 + rg);
                int col = bn * 256 + wn2 * 64 + nf * 16 + lr;
                #pragma unroll
                for (int rr = 0; rr < 4; ++rr)
                    C[(row0 + rr) * N + col] = acc[mf][nf][rr];
            }
    } else if (MODE == 1) {
        const int h = bn;
        #pragma unroll
        for (int mf = 0; mf < 8; ++mf)
            #pragma unroll
            for (int nf = 0; nf < 4; ++nf) {
                int d = wn2 * 64 + nf * 16 + lr;
                int trow = bm * 256 + wm2 * 128 + mf * 16 + rg;
                int b = trow >> 11, t = trow & 2047;
                if (d < 128) {
                    bf16_t* p = out0 + ((size_t)(b * 16 + h) * SEQ + t) * 192 + d;
                    #pragma unroll
                    for (int rr = 0; rr < 4; ++rr)
                        p[rr * 192] = (bf16_t)acc[mf][nf][rr];
                } else {
                    bf16x4 pv = { (bf16_t)acc[mf][nf][0], (bf16_t)acc[mf][nf][1],
                                  (bf16_t)acc[mf][nf][2], (bf16_t)acc[mf][nf][3] };
                    *(bf16x4*)(out1 + ((size_t)(b * 16 + h) * 128 + (d - 128)) * SEQ + t) = pv;
                }
            }
    } else {
        #pragma unroll
        for (int mf = 0; mf < 8; ++mf)
            #pragma unroll
            for (int nf = 0; nf < 4; ++nf) {
                int n = bn * 256 + wn2 * 64 + nf * 16 + lr;
                int h = n / 192, d = n - h * 192;
                int trow = bm * 256 + wm2 * 128 + mf * 16 + rg;
                int b = trow >> 11, t = trow & 2047;
                bf16_t* p = out0 + ((size_t)(b * 16 + h) * SEQ + t) * 192 + d;
                #pragma unroll
                for (int rr = 0; rr < 4; ++rr)
                    p[rr * 192] = (bf16_t)acc[mf][nf][rr];
            }
    }
}

// ---------------------------------------------------------------------------
// m97-structure 128x128 GEMM (N=576 kv_a and N=2048 wo), XCD swizzle
// ---------------------------------------------------------------------------
__global__ __launch_bounds__(256)
void gemm_nt(const bf16_t* __restrict__ A, const bf16_t* __restrict__ B,
             float* __restrict__ C, int M, int N, int K, int total, int nbn) {
    __shared__ bf16_t As[4096], Bs[4096];
    int bm, bn;
    xcd_map(blockIdx.x, total, nbn, bm, bn);

    const int tid = threadIdx.x;
    const int lane = tid & 63, w = tid >> 6;
    const int lr = lane & 15, kh = lane >> 4;
    const int wm = (w >> 1) * 64, wn = (w & 1) * 64;
    const int subrow = lane >> 2;
    const int colel = (lane & 3) * 8;

    f32x4 acc[4][4];
    #pragma unroll
    for (int i = 0; i < 4; ++i)
        #pragma unroll
        for (int j = 0; j < 4; ++j) acc[i][j] = 0.0f;

    const int rA = bm * 128 + 32 * w + subrow;
    const int rB = bn * 128 + 32 * w + subrow;
    const int rb1 = (rB < N) ? rB : (N - 1);
    const int rb2 = (rB + 16 < N) ? (rB + 16) : (N - 1);

    for (int kt = 0; kt < K; kt += 32) {
        __syncthreads();
        gload_lds16(A + (size_t)rA * K + kt + colel,        As + (2 * w) * 512);
        gload_lds16(A + (size_t)(rA + 16) * K + kt + colel, As + (2 * w + 1) * 512);
        gload_lds16(B + (size_t)rb1 * K + kt + colel,       Bs + (2 * w) * 512);
        gload_lds16(B + (size_t)rb2 * K + kt + colel,       Bs + (2 * w + 1) * 512);
        __syncthreads();
        bf16x8 af[4], bfr[4];
        #pragma unroll
        for (int im = 0; im < 4; ++im)
            af[im] = *(const bf16x8*)(As + (wm + im * 16 + lr) * 32 + kh * 8);
        #pragma unroll
        for (int jn = 0; jn < 4; ++jn)
            bfr[jn] = *(const bf16x8*)(Bs + (wn + jn * 16 + lr) * 32 + kh * 8);
        #pragma unroll
        for (int im = 0; im < 4; ++im)
            #pragma unroll
            for (int jn = 0; jn < 4; ++jn)
                acc[im][jn] = __builtin_amdgcn_mfma_f32_16x16x32_bf16(
                    af[im], bfr[jn], acc[im][jn], 0, 0, 0);
    }

    const int rg = kh * 4;
    #pragma unroll
    for (int im = 0; im < 4; ++im)
        #pragma unroll
        for (int jn = 0; jn < 4; ++jn) {
            int col = bn * 128 + wn + jn * 16 + lr;
            if (col >= N) continue;
            size_t rowb = (size_t)(bm * 128 + wm + im * 16 + rg);
            #pragma unroll
            for (int rr = 0; rr < 4; ++rr)
                C[(rowb + rr) * N + col] = acc[im][jn][rr];
        }
}

// ---------------------------------------------------------------------------
// Fused: layernorm(kv)->kvnb (bf16), rope(k_pe)->K_pack broadcast,
// rope cos/sin table (b==0 blocks).
// ---------------------------------------------------------------------------
__global__ __launch_bounds__(256)
void rope_ln(const float* __restrict__ kv_all,
             const float* __restrict__ lnw, const float* __restrict__ lnb,
             bf16_t* __restrict__ kvnb, bf16_t* __restrict__ kpack,
             float2* __restrict__ rope_cs, const int* __restrict__ start_pos) {
    const int m = blockIdx.x;
    const int tid = threadIdx.x;
    const int b = m >> 11, t = m & 2047;
    const float pos = (float)(start_pos[0] + t);
    __shared__ float red[8];
    __shared__ float stats[2];
    __shared__ float kbuf[64];

    const float* kvrow = kv_all + (size_t)m * 576;
    float v0 = kvrow[tid], v1 = kvrow[tid + 256];
    float ssum = v0 + v1, ssq = v0 * v0 + v1 * v1;
    for (int off = 32; off > 0; off >>= 1) {
        ssum += __shfl_down(ssum, off);
        ssq  += __shfl_down(ssq, off);
    }
    const int lane = tid & 63, wid = tid >> 6;
    if (lane == 0) { red[wid] = ssum; red[4 + wid] = ssq; }
    __syncthreads();
    if (tid == 0) {
        float ts = red[0] + red[1] + red[2] + red[3];
        float tq = red[4] + red[5] + red[6] + red[7];
        float mu = ts * (1.0f / 512.0f);
        float var = tq * (1.0f / 512.0f) - mu * mu;
        stats[0] = mu;
        stats[1] = rsqrtf(var + LN_EPS);
    }
    if (tid < 32) {
        int j = tid;
        float inv = expf(-(float)j * 0.2878231366242554f);  // 10000^(-j/32)
        float ang = pos * inv;
        float c = cosf(ang), sn = sinf(ang);
        float x1 = kvrow[512 + j], x2 = kvrow[544 + j];
        kbuf[j]      = x1 * c - x2 * sn;
        kbuf[32 + j] = x2 * c + x1 * sn;
        if (b == 0) rope_cs[t * 32 + j] = make_float2(c, sn);
    }
    __syncthreads();
    float mu = stats[0], rstd = stats[1];
    kvnb[(size_t)m * 512 + tid]       = (bf16_t)((v0 - mu) * rstd * lnw[tid] + lnb[tid]);
    kvnb[(size_t)m * 512 + tid + 256] = (bf16_t)((v1 - mu) * rstd * lnw[tid + 256] + lnb[tid + 256]);

    {
        int hh = tid >> 4, j4 = (tid & 15) * 4;
        bf16x4 pk = { (bf16_t)kbuf[j4], (bf16_t)kbuf[j4 + 1],
                      (bf16_t)kbuf[j4 + 2], (bf16_t)kbuf[j4 + 3] };
        *(bf16x4*)(kpack + ((size_t)(b * 16 + hh) * SEQ + t) * 192 + 128 + j4) = pk;
    }
}

// ---------------------------------------------------------------------------
// MFMA flash attention v3: 512 paired blocks {31-bx,bx}, 4 waves.
// Wave w = (tq=w&1, qh=w>>1) computes the (t-half, q-half) quadrant of QK:
// every K fragment read feeds TWO Q fragments -> K LDS reads halved.
// Softmax combined across the tq-pair via small LDS arrays with a
// branchless per-q defer-max update (deterministic; still 2 barriers/step).
// K staged by global_load_lds DMA (pre-swizzled source, dbuf); V reg-staged.
// PV identical to round-10 (wave owns q-slice w*16..+16).
// ---------------------------------------------------------------------------
__global__ __launch_bounds__(256, 2)
void attn_mfma(const bf16_t* __restrict__ qb, const bf16_t* __restrict__ kpack,
               const bf16_t* __restrict__ vt, const float2* __restrict__ rope_cs,
               bf16_t* __restrict__ ao) {
    __shared__ __attribute__((aligned(16))) bf16_t Ks[2][64 * 192]; // 48KB
    __shared__ __attribute__((aligned(16))) bf16_t Vts[128 * 64];   // 16KB
    __shared__ __attribute__((aligned(16))) bf16_t Pls[64 * 64];    // 8KB
    __shared__ float pmls[2][64];
    __shared__ float psls[2][64];

    const int bid = blockIdx.x;
    const int xcd = bid & 7, s = bid >> 3;       // s: 0..63
    const int grp = xcd * 4 + (s >> 4);          // group 0..31
    const int bx = s & 15;
    const int h = grp & 15, b = grp >> 4;

    const int tid = threadIdx.x;
    const int lane = tid & 63, w = tid >> 6;
    const int lr = lane & 15, kh = lane >> 4;
    const int lr7 = lr & 7;
    const int tq = w & 1, qh = w >> 1;
    const int e0 = kh ^ lr7;
    const int e1 = (4 + kh) ^ lr7;
    const size_t bS = (size_t)b * SEQ;
    const bf16_t* kbase = kpack + (size_t)(b * 16 + h) * SEQ * 192;
    const bf16_t* vbase = vt + (size_t)(b * 16 + h) * 128 * SEQ;

    // K DMA source map: 6 chunks/thread; chunk c=(i*4+w)*64+lane at linear
    // LDS pos c; source slot = swizzle-involution so swizzled READS are correct.
    int kgo_[6];
    #pragma unroll
    for (int i = 0; i < 6; ++i) {
        int c = (i * 4 + w) * 64 + lane;
        int row = c / 24, sl = c % 24;
        kgo_[i] = row * 192 + ((sl & 24) | ((sl ^ row) & 7)) * 8;
    }
    // V reg-stage maps (4/thread)
    int vgo_[4], vlo_[4];
    #pragma unroll
    for (int i = 0; i < 4; ++i) {
        int c = tid + 256 * i;
        int d = c >> 3, sl = c & 7;
        vgo_[i] = d * SEQ + sl * 8;
        vlo_[i] = d * 64 + ((sl ^ (d & 7)) * 8);
    }

    for (int half = 0; half < 2; ++half) {
        const int qt = half ? bx : (31 - bx);
        const int q0 = qt * 64;

        // QK-role local q's: q2[g] = qh*32 + g*16 + lr
        // Q fragments (bf16) + in-register rope on ks=4/5
        bf16x8 qf[2][6];
        #pragma unroll
        for (int g = 0; g < 2; ++g) {
            const int qa = q0 + qh * 32 + g * 16 + lr;
            const bf16_t* qrow = qb + ((size_t)(b * 16 + h) * SEQ + qa) * 192;
            #pragma unroll
            for (int ks = 0; ks < 6; ++ks)
                qf[g][ks] = *(const bf16x8*)(qrow + ks * 32 + kh * 8);
            const float2* csp = rope_cs + (size_t)qa * 32 + kh * 8;
            #pragma unroll
            for (int i = 0; i < 8; ++i) {
                float2 cs = csp[i];
                float x1 = (float)qf[g][4][i], x2 = (float)qf[g][5][i];
                qf[g][4][i] = (bf16_t)(x1 * cs.x - x2 * cs.y);
                qf[g][5][i] = (bf16_t)(x2 * cs.x + x1 * cs.y);
            }
        }

        f32x4 O[8];
        #pragma unroll
        for (int i = 0; i < 8; ++i) O[i] = 0.0f;
        float m_qk[2] = { -1e30f, -1e30f };
        float l_r = 0.0f;

        int cur = 0;
        // prologue: K[0] DMA -> Ks[0]; V[0] -> regs
        #pragma unroll
        for (int i = 0; i < 6; ++i)
            gload_lds16(kbase + kgo_[i], Ks[0] + (i * 4 + w) * 512);
        bf16x8 rv[4];
        #pragma unroll
        for (int i = 0; i < 4; ++i)
            rv[i] = *(const bf16x8*)(vbase + vgo_[i]);
        __syncthreads();

        for (int kt = 0; kt <= qt; ++kt) {
            const bf16_t* kcur = Ks[cur];
            if (kt < qt) {   // DMA K[kt+1] into other buffer
                #pragma unroll
                for (int i = 0; i < 6; ++i)
                    gload_lds16(kbase + (size_t)(kt + 1) * 12288 + kgo_[i],
                                Ks[cur ^ 1] + (i * 4 + w) * 512);
            }

            // QK quadrant: D[32t x 32q]; each kf feeds both q-groups
            f32x4 sacc[2][2];
            #pragma unroll
            for (int tj = 0; tj < 2; ++tj)
                #pragma unroll
                for (int g = 0; g < 2; ++g) sacc[tj][g] = 0.0f;
            __builtin_amdgcn_s_setprio(1);
            #pragma unroll
            for (int ks = 0; ks < 6; ++ks) {
                const int sw = (ks >> 1) * 64 + ((ks & 1) ? e1 : e0) * 8;
                #pragma unroll
                for (int tj = 0; tj < 2; ++tj) {
                    bf16x8 kf = *(const bf16x8*)(kcur + (tq * 32 + tj * 16 + lr) * 192 + sw);
                    sacc[tj][0] = __builtin_amdgcn_mfma_f32_16x16x32_bf16(kf, qf[0][ks], sacc[tj][0], 0, 0, 0);
                    sacc[tj][1] = __builtin_amdgcn_mfma_f32_16x16x32_bf16(kf, qf[1][ks], sacc[tj][1], 0, 0, 0);
                }
            }
            __builtin_amdgcn_s_setprio(0);

            const int t0 = kt * 64;
            float p[2][2][4];   // [tj][g][rr]
            if (kt == qt) {
                #pragma unroll
                for (int tj = 0; tj < 2; ++tj)
                    #pragma unroll
                    for (int g = 0; g < 2; ++g)
                        #pragma unroll
                        for (int rr = 0; rr < 4; ++rr) {
                            int tabs = t0 + tq * 32 + tj * 16 + kh * 4 + rr;
                            int qa = q0 + qh * 32 + g * 16 + lr;
                            p[tj][g][rr] = (tabs > qa) ? -1e30f : sacc[tj][g][rr] * MLA_SCALE;
                        }
            } else {
                #pragma unroll
                for (int tj = 0; tj < 2; ++tj)
                    #pragma unroll
                    for (int g = 0; g < 2; ++g)
                        #pragma unroll
                        for (int rr = 0; rr < 4; ++rr)
                            p[tj][g][rr] = sacc[tj][g][rr] * MLA_SCALE;
            }

            // partial max per q-group over this wave's 32 t's
            float pmax[2];
            #pragma unroll
            for (int g = 0; g < 2; ++g) {
                float mx = p[0][g][0];
                #pragma unroll
                for (int e = 1; e < 4; ++e) mx = fmaxf(mx, p[0][g][e]);
                #pragma unroll
                for (int e = 0; e < 4; ++e) mx = fmaxf(mx, p[1][g][e]);
                mx = fmaxf(mx, __shfl_xor(mx, 16));
                mx = fmaxf(mx, __shfl_xor(mx, 32));
                pmax[g] = mx;
            }
            if (kh == 0) {
                pmls[tq][qh * 32 + lr] = pmax[0];
                pmls[tq][qh * 32 + 16 + lr] = pmax[1];
            }
            __syncthreads();   // B_a (drains K DMA; all PV[kt-1] done)

            // combine + branchless per-q defer-max (deterministic across waves)
            float cr[2];
            #pragma unroll
            for (int g = 0; g < 2; ++g) {
                int q2 = qh * 32 + g * 16 + lr;
                float mx2 = fmaxf(pmls[0][q2], pmls[1][q2]);
                float mn = (mx2 > m_qk[g] + 8.0f) ? mx2 : m_qk[g];
                cr[g] = __expf(m_qk[g] - mn);
                m_qk[g] = mn;
            }
            // O rescale (PV q-slice = QK group g = w&1)
            float crp = cr[w & 1];
            l_r *= crp;
            float corr[4];
            #pragma unroll
            for (int rr = 0; rr < 4; ++rr)
                corr[rr] = __shfl(crp, kh * 4 + rr);
            #pragma unroll
            for (int dt = 0; dt < 8; ++dt)
                #pragma unroll
                for (int rr = 0; rr < 4; ++rr)
                    O[dt][rr] *= corr[rr];

            // P = exp, partial sums, writes
            float ps2[2] = { 0.0f, 0.0f };
            #pragma unroll
            for (int tj = 0; tj < 2; ++tj)
                #pragma unroll
                for (int g = 0; g < 2; ++g)
                    #pragma unroll
                    for (int rr = 0; rr < 4; ++rr) {
                        float e = __expf(p[tj][g][rr] - m_qk[g]);
                        p[tj][g][rr] = e;
                        ps2[g] += e;
                    }
            #pragma unroll
            for (int g = 0; g < 2; ++g) {
                ps2[g] += __shfl_xor(ps2[g], 16);
                ps2[g] += __shfl_xor(ps2[g], 32);
            }
            if (kh == 0) {
                psls[tq][qh * 32 + lr] = ps2[0];
                psls[tq][qh * 32 + 16 + lr] = ps2[1];
            }
            // P quadrant -> Pls[64q][64t] (slot swizzled by q&7 = lr7)
            #pragma unroll
            for (int tj = 0; tj < 2; ++tj)
                #pragma unroll
                for (int g = 0; g < 2; ++g) {
                    int q2 = qh * 32 + g * 16 + lr;
                    int slot = tq * 4 + tj * 2 + (kh >> 1);
                    bf16x4 pp = { (bf16_t)p[tj][g][0], (bf16_t)p[tj][g][1],
                                  (bf16_t)p[tj][g][2], (bf16_t)p[tj][g][3] };
                    *(bf16x4*)(Pls + q2 * 64 + ((slot ^ lr7) * 8) + (kh & 1) * 4) = pp;
                }
            // V[kt] write from regs
            #pragma unroll
            for (int i = 0; i < 4; ++i) *(bf16x8*)(Vts + vlo_[i]) = rv[i];
            __syncthreads();   // B_b

            if (kt < qt) {   // V[kt+1] reg prefetch (issued post-barrier)
                #pragma unroll
                for (int i = 0; i < 4; ++i)
                    rv[i] = *(const bf16x8*)(vbase + vgo_[i] + (kt + 1) * 64);
            }

            // PV: wave owns q-slice w*16..+16
            const bf16_t* pw = Pls + (w * 16 + lr) * 64;
            bf16x8 pa0 = *(const bf16x8*)(pw + e0 * 8);
            bf16x8 pa1 = *(const bf16x8*)(pw + e1 * 8);
            __builtin_amdgcn_s_setprio(1);
            #pragma unroll
            for (int dt = 0; dt < 8; ++dt) {
                bf16x8 b0 = *(const bf16x8*)(Vts + (dt * 16 + lr) * 64 + e0 * 8);
                O[dt] = __builtin_amdgcn_mfma_f32_16x16x32_bf16(pa0, b0, O[dt], 0, 0, 0);
                bf16x8 b1 = *(const bf16x8*)(Vts + (dt * 16 + lr) * 64 + e1 * 8);
                O[dt] = __builtin_amdgcn_mfma_f32_16x16x32_bf16(pa1, b1, O[dt], 0, 0, 0);
            }
            __builtin_amdgcn_s_setprio(0);

            // l update from combined partial sums
            l_r += psls[0][w * 16 + lr] + psls[1][w * 16 + lr];
            cur ^= 1;
        }

        // epilogue
        float linv[4];
        #pragma unroll
        for (int rr = 0; rr < 4; ++rr)
            linv[rr] = 1.0f / __shfl(l_r, kh * 4 + rr);
        #pragma unroll
        for (int rr = 0; rr < 4; ++rr) {
            size_t rowb = (bS + q0 + w * 16 + kh * 4 + rr) * 2048 + h * 128;
            #pragma unroll
            for (int dt = 0; dt < 8; ++dt)
                ao[rowb + dt * 16 + lr] = (bf16_t)(O[dt][rr] * linv[rr]);
        }
        __syncthreads();
    }
}

// ---------------------------------------------------------------------------
extern "C" void kernel_launch(void* const* d_in, const int* in_sizes, int n_in,
                              void* d_out, int out_size, void* d_ws, size_t ws_size,
                              hipStream_t stream) {
    const float* x     = (const float*)d_in[0];
    const float* wq    = (const float*)d_in[1];
    const float* wkv_a = (const float*)d_in[2];
    const float* lnw   = (const float*)d_in[3];
    const float* lnb   = (const float*)d_in[4];
    const float* wkv_b = (const float*)d_in[5];
    const float* wo    = (const float*)d_in[6];
    const int* start_pos = (const int*)d_in[7];
    float* out = (float*)d_out;

    char* w8 = (char*)d_ws;
    bf16_t* xb   = (bf16_t*)(w8);                  // 16777216 B
    bf16_t* wqb  = (bf16_t*)(w8 + 16777216);       // 12582912 B
    bf16_t* wab  = (bf16_t*)(w8 + 29360128);       //  2359296 B
    bf16_t* wbb  = (bf16_t*)(w8 + 31719424);       //  4194304 B
    bf16_t* wob  = (bf16_t*)(w8 + 35913728);       //  8388608 B
    bf16_t* kvnb = (bf16_t*)(w8 + 44302336);       //  4194304 B
    bf16_t* kpk  = (bf16_t*)(w8 + 48496640);       // 25165824 B (K_pack)
    bf16_t* vtb  = (bf16_t*)(w8 + 73662464);       // 16777216 B (Vt)
    bf16_t* aob  = (bf16_t*)(w8 + 90439680);       // 16777216 B
    bf16_t* qbh  = (bf16_t*)(w8 + 107216896);      // 25165824 B (q bf16 head-major)
    float*  kva  = (float*)(w8 + 132382720);       //  9437184 B fp32
    float2* rcs  = (float2*)(w8 + 141819904);      //   524288 B (rope table)

    cvt_all<<<2048, 256, 0, stream>>>(x, wq, wkv_a, wkv_b, wo, xb, wqb, wab, wbb, wob);

    // q = x @ wq.T -> bf16 head-major q[b,h,t,192]
    gemm256<2><<<192, 512, 0, stream>>>(xb, wqb, nullptr, qbh, nullptr, 3072, 2048, 192, 12);
    // kv_all = x @ wkv_a.T (128^2, N=576)
    gemm_nt<<<160, 256, 0, stream>>>(xb, wab, kva, 4096, 576, 2048, 160, 5);
    // layernorm + k_pe rope + rope table
    rope_ln<<<4096, 256, 0, stream>>>(kva, lnw, lnb, kvnb, kpk, rcs, start_pos);
    // k_nope/v -> K_pack/Vt
    gemm256<1><<<256, 512, 0, stream>>>(kvnb, wbb, nullptr, kpk, vtb, 4096, 512, 256, 16);
    // attention (512 paired blocks, quadrant QK with shared K reads)
    attn_mfma<<<512, 256, 0, stream>>>(qbh, kpk, vtb, rcs, aob);
    // out = ao @ wo.T (128^2)
    gemm_nt<<<512, 256, 0, stream>>>(aob, wob, out, 4096, 2048, 2048, 512, 16);
}

// Round 14
// 274.874 us; speedup vs baseline: 1.1374x; 1.0375x over previous
//
#include <hip/hip_runtime.h>
#include <hip/hip_bf16.h>
#include <math.h>

typedef __bf16 bf16_t;
typedef __bf16 bf16x2 __attribute__((ext_vector_type(2)));
typedef __bf16 bf16x4 __attribute__((ext_vector_type(4)));
typedef __bf16 bf16x8 __attribute__((ext_vector_type(8)));
typedef float f32x4 __attribute__((ext_vector_type(4)));

#define SEQ 2048
#define MLA_SCALE 0.07216878364870322f
#define LN_EPS 1e-5f

__device__ __forceinline__ void gload_lds16(const bf16_t* g, bf16_t* l) {
    __builtin_amdgcn_global_load_lds(
        (const __attribute__((address_space(1))) uint32_t*)(const void*)g,
        (__attribute__((address_space(3))) uint32_t*)(void*)l, 16, 0, 0);
}

// bijective XCD-aware block swizzle
__device__ __forceinline__ void xcd_map(int bid, int total, int nbn,
                                        int& bm, int& bn) {
    int per = total >> 3;
    int cbm = per / nbn;
    int xcd = bid & 7, s = bid >> 3;
    int q = s / nbn;
    bm = xcd * cbm + q;
    bn = s - q * nbn;
}

// ---------------------------------------------------------------------------
// fused fp32 -> bf16 convert of all 5 buffers (one launch)
// ---------------------------------------------------------------------------
#define CVT_N0 2097152   // x      (float4 units)
#define CVT_N1 1572864   // wq
#define CVT_N2 294912    // wkv_a
#define CVT_N3 524288    // wkv_b
#define CVT_N4 1048576   // wo
#define CVT_TOT (CVT_N0 + CVT_N1 + CVT_N2 + CVT_N3 + CVT_N4)

__global__ __launch_bounds__(256)
void cvt_all(const float* __restrict__ x, const float* __restrict__ wq,
             const float* __restrict__ wa, const float* __restrict__ wb,
             const float* __restrict__ wo, bf16_t* __restrict__ xb,
             bf16_t* __restrict__ wqb, bf16_t* __restrict__ wab,
             bf16_t* __restrict__ wbb, bf16_t* __restrict__ wob) {
    for (int i = blockIdx.x * 256 + threadIdx.x; i < CVT_TOT; i += gridDim.x * 256) {
        const float* src; bf16_t* dst; int off = i;
        if (i < CVT_N0) { src = x; dst = xb; }
        else if (i < CVT_N0 + CVT_N1) { src = wq; dst = wqb; off = i - CVT_N0; }
        else if (i < CVT_N0 + CVT_N1 + CVT_N2) { src = wa; dst = wab; off = i - CVT_N0 - CVT_N1; }
        else if (i < CVT_N0 + CVT_N1 + CVT_N2 + CVT_N3) { src = wb; dst = wbb; off = i - CVT_N0 - CVT_N1 - CVT_N2; }
        else { src = wo; dst = wob; off = i - CVT_N0 - CVT_N1 - CVT_N2 - CVT_N3; }
        float4 v = ((const float4*)src)[off];
        bf16x4 p = { (bf16_t)v.x, (bf16_t)v.y, (bf16_t)v.z, (bf16_t)v.w };
        ((bf16x4*)dst)[off] = p;
    }
}

// ===========================================================================
// 256x256 8-phase GEMM. C[M,N] = A[M,K] * B[N,K]^T, bf16 in, fp32 acc.
// MODE 0: fp32 C.  MODE 1: kvb pack (K_pack + Vt).  MODE 2: q bf16 head-major.
// ===========================================================================
#define G256_PHASE(TAU, KS, MH, HTO, MAT, WAITV)                               \
{                                                                              \
    const int slot_ = (2 * (TAU) + (KS)) & 3;                                  \
    bf16x8 af_[4];                                                             \
    {                                                                          \
        const bf16_t* ab_ = As + slot_ * 8192 +                                \
                            (wm2 * 128 + (MH) * 64 + lr) * 32 + rdcol;         \
        _Pragma("unroll")                                                      \
        for (int f = 0; f < 4; ++f) af_[f] = *(const bf16x8*)(ab_ + f * 512);  \
    }                                                                          \
    if ((MH) == 0) {                                                           \
        const bf16_t* bb_ = Bs + slot_ * 8192 + (wn2 * 64 + lr) * 32 + rdcol;  \
        _Pragma("unroll")                                                      \
        for (int f = 0; f < 4; ++f) bq[f] = *(const bf16x8*)(bb_ + f * 512);   \
    }                                                                          \
    if ((MAT) == 0) stageA(2 * T + 3 + (HTO)); else stageB(2 * T + 3 + (HTO)); \
    __builtin_amdgcn_s_barrier();                                              \
    asm volatile("" ::: "memory");                                             \
    __builtin_amdgcn_s_setprio(1);                                             \
    _Pragma("unroll")                                                          \
    for (int f = 0; f < 4; ++f)                                                \
        _Pragma("unroll")                                                      \
        for (int n = 0; n < 4; ++n)                                            \
            acc[(MH) * 4 + f][n] = __builtin_amdgcn_mfma_f32_16x16x32_bf16(    \
                af_[f], bq[n], acc[(MH) * 4 + f][n], 0, 0, 0);                 \
    __builtin_amdgcn_s_setprio(0);                                             \
    asm volatile("" ::: "memory");                                             \
    if (WAITV) asm volatile("s_waitcnt vmcnt(8)" ::: "memory");                \
    __builtin_amdgcn_s_barrier();                                              \
}

template<int MODE>
__global__ __launch_bounds__(512, 2)
void gemm256(const bf16_t* __restrict__ A, const bf16_t* __restrict__ B,
             float* __restrict__ C, bf16_t* __restrict__ out0,
             bf16_t* __restrict__ out1, int N, int K, int total, int nbn) {
    __shared__ __attribute__((aligned(16))) bf16_t As[32768];
    __shared__ __attribute__((aligned(16))) bf16_t Bs[32768];
    __shared__ __attribute__((aligned(16))) bf16_t Ds[8192];

    const int tid = threadIdx.x;
    const int lane = tid & 63, w = tid >> 6;
    const int lr = lane & 15, kh = lane >> 4;
    const int wm2 = w >> 2, wn2 = w & 3;
    int bm, bn;
    xcd_map(blockIdx.x, total, nbn, bm, bn);
    const int NT = K >> 6;

    const int rdcol = 8 * (kh ^ ((lr >> 1) & 3));
    const int strow = (w << 5) + (lane >> 2);
    const int scol = 8 * ((lane & 3) ^ ((lane >> 3) & 3));

    f32x4 acc[8][4];
    #pragma unroll
    for (int i = 0; i < 8; ++i)
        #pragma unroll
        for (int j = 0; j < 4; ++j) acc[i][j] = 0.0f;

    auto stageA = [&](int ht) {
        int hs = (ht < 2 * NT) ? ht : (2 * NT - 1);
        int tau = hs >> 1, kap = hs & 1;
        const bf16_t* g = A + (size_t)(bm * 256 + strow) * K + tau * 64 + kap * 32 + scol;
        bf16_t* l = (ht < 2 * NT) ? (As + (ht & 3) * 8192 + w * 1024) : (Ds + w * 1024);
        gload_lds16(g, l);
        gload_lds16(g + (size_t)16 * K, l + 512);
    };
    auto stageB = [&](int ht) {
        int hs = (ht < 2 * NT) ? ht : (2 * NT - 1);
        int tau = hs >> 1, kap = hs & 1;
        const bf16_t* g = B + (size_t)(bn * 256 + strow) * K + tau * 64 + kap * 32 + scol;
        bf16_t* l = (ht < 2 * NT) ? (Bs + (ht & 3) * 8192 + w * 1024) : (Ds + w * 1024);
        gload_lds16(g, l);
        gload_lds16(g + (size_t)16 * K, l + 512);
    };

    stageA(0); stageB(0); stageA(1); stageB(1); stageA(2); stageB(2);
    asm volatile("s_waitcnt vmcnt(8)" ::: "memory");
    __builtin_amdgcn_s_barrier();

    for (int it = 0; it < (NT >> 1); ++it) {
        const int T = 2 * it;
        bf16x8 bq[4];
        G256_PHASE(T,     0, 0, 0, 0, 0)
        G256_PHASE(T,     0, 1, 0, 1, 1)
        G256_PHASE(T,     1, 0, 1, 0, 0)
        G256_PHASE(T,     1, 1, 1, 1, 1)
        G256_PHASE(T + 1, 0, 0, 2, 0, 0)
        G256_PHASE(T + 1, 0, 1, 2, 1, 1)
        G256_PHASE(T + 1, 1, 0, 3, 0, 0)
        G256_PHASE(T + 1, 1, 1, 3, 1, 1)
    }

    const int rg = kh * 4;
    if (MODE == 0) {
        #pragma unroll
        for (int mf = 0; mf < 8; ++mf)
            #pragma unroll
            for (int nf = 0; nf < 4; ++nf) {
                size_t row0 = (size_t)(bm * 256 + wm2 * 128 + mf * 16 + rg);
                int col = bn * 256 + wn2 * 64 + nf * 16 + lr;
                #pragma unroll
                for (int rr = 0; rr < 4; ++rr)
                    C[(row0 + rr) * N + col] = acc[mf][nf][rr];
            }
    } else if (MODE == 1) {
        const int h = bn;
        #pragma unroll
        for (int mf = 0; mf < 8; ++mf)
            #pragma unroll
            for (int nf = 0; nf < 4; ++nf) {
                int d = wn2 * 64 + nf * 16 + lr;
                int trow = bm * 256 + wm2 * 128 + mf * 16 + rg;
                int b = trow >> 11, t = trow & 2047;
                if (d < 128) {
                    bf16_t* p = out0 + ((size_t)(b * 16 + h) * SEQ + t) * 192 + d;
                    #pragma unroll
                    for (int rr = 0; rr < 4; ++rr)
                        p[rr * 192] = (bf16_t)acc[mf][nf][rr];
                } else {
                    bf16x4 pv = { (bf16_t)acc[mf][nf][0], (bf16_t)acc[mf][nf][1],
                                  (bf16_t)acc[mf][nf][2], (bf16_t)acc[mf][nf][3] };
                    *(bf16x4*)(out1 + ((size_t)(b * 16 + h) * 128 + (d - 128)) * SEQ + t) = pv;
                }
            }
    } else {
        #pragma unroll
        for (int mf = 0; mf < 8; ++mf)
            #pragma unroll
            for (int nf = 0; nf < 4; ++nf) {
                int n = bn * 256 + wn2 * 64 + nf * 16 + lr;
                int h = n / 192, d = n - h * 192;
                int trow = bm * 256 + wm2 * 128 + mf * 16 + rg;
                int b = trow >> 11, t = trow & 2047;
                bf16_t* p = out0 + ((size_t)(b * 16 + h) * SEQ + t) * 192 + d;
                #pragma unroll
                for (int rr = 0; rr < 4; ++rr)
                    p[rr * 192] = (bf16_t)acc[mf][nf][rr];
            }
    }
}

// ---------------------------------------------------------------------------
// m97-structure 128x128 GEMM (N=576 kv_a and N=2048 wo), XCD swizzle
// ---------------------------------------------------------------------------
__global__ __launch_bounds__(256)
void gemm_nt(const bf16_t* __restrict__ A, const bf16_t* __restrict__ B,
             float* __restrict__ C, int M, int N, int K, int total, int nbn) {
    __shared__ bf16_t As[4096], Bs[4096];
    int bm, bn;
    xcd_map(blockIdx.x, total, nbn, bm, bn);

    const int tid = threadIdx.x;
    const int lane = tid & 63, w = tid >> 6;
    const int lr = lane & 15, kh = lane >> 4;
    const int wm = (w >> 1) * 64, wn = (w & 1) * 64;
    const int subrow = lane >> 2;
    const int colel = (lane & 3) * 8;

    f32x4 acc[4][4];
    #pragma unroll
    for (int i = 0; i < 4; ++i)
        #pragma unroll
        for (int j = 0; j < 4; ++j) acc[i][j] = 0.0f;

    const int rA = bm * 128 + 32 * w + subrow;
    const int rB = bn * 128 + 32 * w + subrow;
    const int rb1 = (rB < N) ? rB : (N - 1);
    const int rb2 = (rB + 16 < N) ? (rB + 16) : (N - 1);

    for (int kt = 0; kt < K; kt += 32) {
        __syncthreads();
        gload_lds16(A + (size_t)rA * K + kt + colel,        As + (2 * w) * 512);
        gload_lds16(A + (size_t)(rA + 16) * K + kt + colel, As + (2 * w + 1) * 512);
        gload_lds16(B + (size_t)rb1 * K + kt + colel,       Bs + (2 * w) * 512);
        gload_lds16(B + (size_t)rb2 * K + kt + colel,       Bs + (2 * w + 1) * 512);
        __syncthreads();
        bf16x8 af[4], bfr[4];
        #pragma unroll
        for (int im = 0; im < 4; ++im)
            af[im] = *(const bf16x8*)(As + (wm + im * 16 + lr) * 32 + kh * 8);
        #pragma unroll
        for (int jn = 0; jn < 4; ++jn)
            bfr[jn] = *(const bf16x8*)(Bs + (wn + jn * 16 + lr) * 32 + kh * 8);
        #pragma unroll
        for (int im = 0; im < 4; ++im)
            #pragma unroll
            for (int jn = 0; jn < 4; ++jn)
                acc[im][jn] = __builtin_amdgcn_mfma_f32_16x16x32_bf16(
                    af[im], bfr[jn], acc[im][jn], 0, 0, 0);
    }

    const int rg = kh * 4;
    #pragma unroll
    for (int im = 0; im < 4; ++im)
        #pragma unroll
        for (int jn = 0; jn < 4; ++jn) {
            int col = bn * 128 + wn + jn * 16 + lr;
            if (col >= N) continue;
            size_t rowb = (size_t)(bm * 128 + wm + im * 16 + rg);
            #pragma unroll
            for (int rr = 0; rr < 4; ++rr)
                C[(rowb + rr) * N + col] = acc[im][jn][rr];
        }
}

// ---------------------------------------------------------------------------
// Fused: layernorm(kv)->kvnb (bf16), rope(k_pe)->K_pack broadcast,
// rope cos/sin table (b==0 blocks).
// ---------------------------------------------------------------------------
__global__ __launch_bounds__(256)
void rope_ln(const float* __restrict__ kv_all,
             const float* __restrict__ lnw, const float* __restrict__ lnb,
             bf16_t* __restrict__ kvnb, bf16_t* __restrict__ kpack,
             float2* __restrict__ rope_cs, const int* __restrict__ start_pos) {
    const int m = blockIdx.x;
    const int tid = threadIdx.x;
    const int b = m >> 11, t = m & 2047;
    const float pos = (float)(start_pos[0] + t);
    __shared__ float red[8];
    __shared__ float stats[2];
    __shared__ float kbuf[64];

    const float* kvrow = kv_all + (size_t)m * 576;
    float v0 = kvrow[tid], v1 = kvrow[tid + 256];
    float ssum = v0 + v1, ssq = v0 * v0 + v1 * v1;
    for (int off = 32; off > 0; off >>= 1) {
        ssum += __shfl_down(ssum, off);
        ssq  += __shfl_down(ssq, off);
    }
    const int lane = tid & 63, wid = tid >> 6;
    if (lane == 0) { red[wid] = ssum; red[4 + wid] = ssq; }
    __syncthreads();
    if (tid == 0) {
        float ts = red[0] + red[1] + red[2] + red[3];
        float tq = red[4] + red[5] + red[6] + red[7];
        float mu = ts * (1.0f / 512.0f);
        float var = tq * (1.0f / 512.0f) - mu * mu;
        stats[0] = mu;
        stats[1] = rsqrtf(var + LN_EPS);
    }
    if (tid < 32) {
        int j = tid;
        float inv = expf(-(float)j * 0.2878231366242554f);  // 10000^(-j/32)
        float ang = pos * inv;
        float c = cosf(ang), sn = sinf(ang);
        float x1 = kvrow[512 + j], x2 = kvrow[544 + j];
        kbuf[j]      = x1 * c - x2 * sn;
        kbuf[32 + j] = x2 * c + x1 * sn;
        if (b == 0) rope_cs[t * 32 + j] = make_float2(c, sn);
    }
    __syncthreads();
    float mu = stats[0], rstd = stats[1];
    kvnb[(size_t)m * 512 + tid]       = (bf16_t)((v0 - mu) * rstd * lnw[tid] + lnb[tid]);
    kvnb[(size_t)m * 512 + tid + 256] = (bf16_t)((v1 - mu) * rstd * lnw[tid + 256] + lnb[tid + 256]);

    {
        int hh = tid >> 4, j4 = (tid & 15) * 4;
        bf16x4 pk = { (bf16_t)kbuf[j4], (bf16_t)kbuf[j4 + 1],
                      (bf16_t)kbuf[j4 + 2], (bf16_t)kbuf[j4 + 3] };
        *(bf16x4*)(kpack + ((size_t)(b * 16 + hh) * SEQ + t) * 192 + 128 + j4) = pk;
    }
}

// ---------------------------------------------------------------------------
// MFMA flash attention (round-10 proven version): paired q-tiles {31-bx,bx}
// (perfect 33-step balance), swapped-operand QK^T, swizzled LDS, K
// double-buffer pipeline (QK overlaps next-K LDS write + K prefetch; V
// single-buffered between barriers). 512 blocks, 256 thr, 2 blocks/CU.
// ---------------------------------------------------------------------------
__global__ __launch_bounds__(256, 2)
void attn_mfma(const bf16_t* __restrict__ qb, const bf16_t* __restrict__ kpack,
               const bf16_t* __restrict__ vt, const float2* __restrict__ rope_cs,
               bf16_t* __restrict__ ao) {
    __shared__ bf16_t Ks[2][64 * 192];  // 48KB, double-buffered
    __shared__ bf16_t Vts[128 * 64];    // 16KB
    __shared__ bf16_t Pls[4 * 16 * 64]; // 8KB, per-wave

    const int bid = blockIdx.x;
    const int xcd = bid & 7, s = bid >> 3;       // s: 0..63
    const int g = xcd * 4 + (s >> 4);            // group 0..31
    const int bx = s & 15;
    const int h = g & 15, b = g >> 4;

    const int tid = threadIdx.x;
    const int lane = tid & 63, w = tid >> 6;
    const int lr = lane & 15, kh = lane >> 4;
    const int lr7 = lr & 7;
    const int e0 = kh ^ lr7;
    const int e1 = (4 + kh) ^ lr7;
    const size_t bS = (size_t)b * SEQ;
    const bf16_t* kbase = kpack + (size_t)(b * 16 + h) * SEQ * 192;
    const bf16_t* vbase = vt + (size_t)(b * 16 + h) * 128 * SEQ;

    // staging maps
    int kgo_[6], klo_[6], vgo_[4], vlo_[4], vco_[4];
    #pragma unroll
    for (int i = 0; i < 6; ++i) {
        int c = tid + 256 * i;
        int row = c / 24, slot = c % 24;
        kgo_[i] = row * 192 + slot * 8;
        klo_[i] = row * 192 + ((slot & 24) | ((slot ^ row) & 7)) * 8;
    }
    #pragma unroll
    for (int i = 0; i < 4; ++i) {
        int c = tid + 256 * i;
        int row = c >> 3, slot = c & 7;
        vgo_[i] = row;
        vlo_[i] = row * 64 + (slot ^ (row & 7)) * 8;
        vco_[i] = slot;
    }

    for (int half = 0; half < 2; ++half) {
        const int qt = half ? bx : (31 - bx);
        const int q0 = qt * 64;
        const int myrow = q0 + w * 16;
        const int qabs = myrow + lr;

        // Q fragments + in-register rope on ks=4/5
        bf16x8 qf[6];
        {
            const bf16_t* qrow = qb + ((size_t)(b * 16 + h) * SEQ + qabs) * 192;
            #pragma unroll
            for (int ks = 0; ks < 6; ++ks)
                qf[ks] = *(const bf16x8*)(qrow + ks * 32 + kh * 8);
            const float2* csp = rope_cs + (size_t)qabs * 32 + kh * 8;
            #pragma unroll
            for (int i = 0; i < 8; ++i) {
                float2 cs = csp[i];
                float x1 = (float)qf[4][i], x2 = (float)qf[5][i];
                qf[4][i] = (bf16_t)(x1 * cs.x - x2 * cs.y);
                qf[5][i] = (bf16_t)(x2 * cs.x + x1 * cs.y);
            }
        }

        f32x4 O[8];
        #pragma unroll
        for (int i = 0; i < 8; ++i) O[i] = 0.0f;
        float m_r = -1e30f, l_r = 0.0f;

        // prologue: K[0] -> Ks[0]; prefetch K[1] into rkw, V[0] into rv
        bf16x8 rkw[6], rkl[6], rv[4];
        {
            bf16x8 rk0[6];
            #pragma unroll
            for (int i = 0; i < 6; ++i)
                rk0[i] = *(const bf16x8*)(kbase + kgo_[i]);
            #pragma unroll
            for (int i = 0; i < 6; ++i)
                *(bf16x8*)(Ks[0] + klo_[i]) = rk0[i];
        }
        {
            const int t1 = (qt > 0 ? 1 : 0) * 64;
            #pragma unroll
            for (int i = 0; i < 6; ++i)
                rkw[i] = *(const bf16x8*)(kbase + (size_t)t1 * 192 + kgo_[i]);
            #pragma unroll
            for (int i = 0; i < 4; ++i)
                rv[i] = *(const bf16x8*)(vbase + (size_t)vgo_[i] * SEQ + vco_[i] * 8);
        }
        __syncthreads();

        for (int kt = 0; kt <= qt; ++kt) {
            const int cur = kt & 1;
            const bf16_t* ksc = Ks[cur];
            bf16_t* ksn = Ks[cur ^ 1];

            // overlap with QK: write next K tile, issue K[kt+2] loads
            if (kt < qt) {
                #pragma unroll
                for (int i = 0; i < 6; ++i)
                    *(bf16x8*)(ksn + klo_[i]) = rkw[i];
            }
            {
                const int tl = (kt + 2 <= qt ? kt + 2 : qt) * 64;
                #pragma unroll
                for (int i = 0; i < 6; ++i)
                    rkl[i] = *(const bf16x8*)(kbase + (size_t)tl * 192 + kgo_[i]);
            }

            // swapped QK^T: D[t][q], q = lr
            f32x4 sacc[4];
            #pragma unroll
            for (int j = 0; j < 4; ++j) sacc[j] = 0.0f;
            __builtin_amdgcn_s_setprio(1);
            #pragma unroll
            for (int ks = 0; ks < 6; ++ks) {
                const int sw = (ks >> 1) * 64 + ((ks & 1) ? e1 : e0) * 8;
                #pragma unroll
                for (int j = 0; j < 4; ++j) {
                    bf16x8 kf = *(const bf16x8*)(ksc + (j * 16 + lr) * 192 + sw);
                    sacc[j] = __builtin_amdgcn_mfma_f32_16x16x32_bf16(kf, qf[ks], sacc[j], 0, 0, 0);
                }
            }
            __builtin_amdgcn_s_setprio(0);

            const int t0 = kt * 64;
            float p[16];
            if (kt == qt) {
                #pragma unroll
                for (int j = 0; j < 4; ++j)
                    #pragma unroll
                    for (int rr = 0; rr < 4; ++rr) {
                        int tabs = t0 + j * 16 + kh * 4 + rr;
                        p[j * 4 + rr] = (tabs > qabs) ? -1e30f : sacc[j][rr] * MLA_SCALE;
                    }
            } else {
                #pragma unroll
                for (int j = 0; j < 4; ++j)
                    #pragma unroll
                    for (int rr = 0; rr < 4; ++rr)
                        p[j * 4 + rr] = sacc[j][rr] * MLA_SCALE;
            }

            float mx = p[0];
            #pragma unroll
            for (int e = 1; e < 16; ++e) mx = fmaxf(mx, p[e]);
            mx = fmaxf(mx, __shfl_xor(mx, 16));
            mx = fmaxf(mx, __shfl_xor(mx, 32));

            if (!__all(mx <= m_r + 8.0f)) {
                float mnew = fmaxf(m_r, mx);
                float cr = __expf(m_r - mnew);
                l_r *= cr;
                m_r = mnew;
                float corr[4];
                #pragma unroll
                for (int rr = 0; rr < 4; ++rr)
                    corr[rr] = __shfl(cr, kh * 4 + rr);
                #pragma unroll
                for (int dt = 0; dt < 8; ++dt)
                    #pragma unroll
                    for (int rr = 0; rr < 4; ++rr)
                        O[dt][rr] *= corr[rr];
            }

            float ps = 0.0f;
            #pragma unroll
            for (int e = 0; e < 16; ++e) {
                p[e] = __expf(p[e] - m_r);
                ps += p[e];
            }
            ps += __shfl_xor(ps, 16);
            ps += __shfl_xor(ps, 32);
            l_r += ps;

            __syncthreads();   // B1: all PV[kt-1] reads done -> Vts overwrite safe
            #pragma unroll
            for (int i = 0; i < 4; ++i) *(bf16x8*)(Vts + vlo_[i]) = rv[i];
            {
                const int tv = (kt + 1 <= qt ? kt + 1 : qt) * 64;
                #pragma unroll
                for (int i = 0; i < 4; ++i)
                    rv[i] = *(const bf16x8*)(vbase + (size_t)vgo_[i] * SEQ + tv + vco_[i] * 8);
            }
            // P -> per-wave LDS (swizzled bf16x4)
            bf16_t* pw = Pls + (w * 16 + lr) * 64;
            const int f2 = kh >> 1, h4 = (kh & 1) * 4;
            #pragma unroll
            for (int j = 0; j < 4; ++j) {
                bf16x4 pp = { (bf16_t)p[j * 4], (bf16_t)p[j * 4 + 1],
                              (bf16_t)p[j * 4 + 2], (bf16_t)p[j * 4 + 3] };
                *(bf16x4*)(pw + ((2 * j + f2) ^ lr7) * 8 + h4) = pp;
            }
            __syncthreads();   // B2: Vts visible
            bf16x8 pa0 = *(const bf16x8*)(pw + e0 * 8);
            bf16x8 pa1 = *(const bf16x8*)(pw + e1 * 8);
            __builtin_amdgcn_s_setprio(1);
            #pragma unroll
            for (int dt = 0; dt < 8; ++dt) {
                bf16x8 b0 = *(const bf16x8*)(Vts + (dt * 16 + lr) * 64 + e0 * 8);
                O[dt] = __builtin_amdgcn_mfma_f32_16x16x32_bf16(pa0, b0, O[dt], 0, 0, 0);
                bf16x8 b1 = *(const bf16x8*)(Vts + (dt * 16 + lr) * 64 + e1 * 8);
                O[dt] = __builtin_amdgcn_mfma_f32_16x16x32_bf16(pa1, b1, O[dt], 0, 0, 0);
            }
            __builtin_amdgcn_s_setprio(0);
            #pragma unroll
            for (int i = 0; i < 6; ++i) rkw[i] = rkl[i];
        }

        // epilogue
        float linv[4];
        #pragma unroll
        for (int rr = 0; rr < 4; ++rr)
            linv[rr] = 1.0f / __shfl(l_r, kh * 4 + rr);
        #pragma unroll
        for (int rr = 0; rr < 4; ++rr) {
            size_t rowb = (bS + myrow + kh * 4 + rr) * 2048 + h * 128;
            #pragma unroll
            for (int dt = 0; dt < 8; ++dt)
                ao[rowb + dt * 16 + lr] = (bf16_t)(O[dt][rr] * linv[rr]);
        }
        __syncthreads();   // protect LDS before next half's prologue writes
    }
}

// ---------------------------------------------------------------------------
extern "C" void kernel_launch(void* const* d_in, const int* in_sizes, int n_in,
                              void* d_out, int out_size, void* d_ws, size_t ws_size,
                              hipStream_t stream) {
    const float* x     = (const float*)d_in[0];
    const float* wq    = (const float*)d_in[1];
    const float* wkv_a = (const float*)d_in[2];
    const float* lnw   = (const float*)d_in[3];
    const float* lnb   = (const float*)d_in[4];
    const float* wkv_b = (const float*)d_in[5];
    const float* wo    = (const float*)d_in[6];
    const int* start_pos = (const int*)d_in[7];
    float* out = (float*)d_out;

    char* w8 = (char*)d_ws;
    bf16_t* xb   = (bf16_t*)(w8);                  // 16777216 B
    bf16_t* wqb  = (bf16_t*)(w8 + 16777216);       // 12582912 B
    bf16_t* wab  = (bf16_t*)(w8 + 29360128);       //  2359296 B
    bf16_t* wbb  = (bf16_t*)(w8 + 31719424);       //  4194304 B
    bf16_t* wob  = (bf16_t*)(w8 + 35913728);       //  8388608 B
    bf16_t* kvnb = (bf16_t*)(w8 + 44302336);       //  4194304 B
    bf16_t* kpk  = (bf16_t*)(w8 + 48496640);       // 25165824 B (K_pack)
    bf16_t* vtb  = (bf16_t*)(w8 + 73662464);       // 16777216 B (Vt)
    bf16_t* aob  = (bf16_t*)(w8 + 90439680);       // 16777216 B
    bf16_t* qbh  = (bf16_t*)(w8 + 107216896);      // 25165824 B (q bf16 head-major)
    float*  kva  = (float*)(w8 + 132382720);       //  9437184 B fp32
    float2* rcs  = (float2*)(w8 + 141819904);      //   524288 B (rope table)

    cvt_all<<<2048, 256, 0, stream>>>(x, wq, wkv_a, wkv_b, wo, xb, wqb, wab, wbb, wob);

    // q = x @ wq.T -> bf16 head-major q[b,h,t,192]
    gemm256<2><<<192, 512, 0, stream>>>(xb, wqb, nullptr, qbh, nullptr, 3072, 2048, 192, 12);
    // kv_all = x @ wkv_a.T (128^2, N=576)
    gemm_nt<<<160, 256, 0, stream>>>(xb, wab, kva, 4096, 576, 2048, 160, 5);
    // layernorm + k_pe rope + rope table
    rope_ln<<<4096, 256, 0, stream>>>(kva, lnw, lnb, kvnb, kpk, rcs, start_pos);
    // k_nope/v -> K_pack/Vt
    gemm256<1><<<256, 512, 0, stream>>>(kvnb, wbb, nullptr, kpk, vtb, 4096, 512, 256, 16);
    // attention (paired q-tiles, 33 steps/block, XCD-grouped)
    attn_mfma<<<512, 256, 0, stream>>>(qbh, kpk, vtb, rcs, aob);
    // out = ao @ wo.T (128^2)
    gemm_nt<<<512, 256, 0, stream>>>(aob, wob, out, 4096, 2048, 2048, 512, 16);
}